// Round 7
// baseline (295.533 us; speedup 1.0000x reference)
//
#include <hip/hip_runtime.h>
#include <math.h>

#define LSEQ   2048
#define DMODEL 1024
#define DINNER 2048
#define DSTATE 16
#define DTRANK 64
#define XCOLS  96   // dt_rank + 2*d_state
#define CL     32   // scan chunk length
#define NC     (LSEQ/CL)          // 64 chunks
#define SSTATE (DINNER*DSTATE)    // 32768 scalar recurrences

typedef __attribute__((ext_vector_type(8))) short bf16x8;
typedef __attribute__((ext_vector_type(4))) float f32x4;
typedef unsigned short ushort_t;
typedef unsigned int uint_t;

__device__ __forceinline__ float siluf(float v) { return v / (1.f + __expf(-v)); }

// RNE float -> bf16 bits (finite inputs)
__device__ __forceinline__ ushort_t f2bf(float f) {
    uint_t u = __float_as_uint(f);
    u += 0x7FFFu + ((u >> 16) & 1u);
    return (ushort_t)(u >> 16);
}

// ---------------------------------------------------------------------------
// fused f32 -> bf16 cast for 3 tensors, 8 elements/thread. sizes % 8 == 0.
// ---------------------------------------------------------------------------
__global__ __launch_bounds__(256)
void cast3_kernel(const float* __restrict__ s0, ushort_t* __restrict__ d0, int c0,
                  const float* __restrict__ s1, ushort_t* __restrict__ d1, int c1,
                  const float* __restrict__ s2, ushort_t* __restrict__ d2, int c2)
{
    int i = (blockIdx.x * 256 + threadIdx.x) * 8;
    const float* s; ushort_t* d;
    if (i < c0)           { s = s0 + i;            d = d0 + i; }
    else if (i < c0 + c1) { s = s1 + (i - c0);     d = d1 + (i - c0); }
    else if (i < c0 + c1 + c2) { s = s2 + (i - c0 - c1); d = d2 + (i - c0 - c1); }
    else return;
    float4 v0 = *(const float4*)s;
    float4 v1 = *(const float4*)(s + 4);
    bf16x8 r;
    r[0] = (short)f2bf(v0.x); r[1] = (short)f2bf(v0.y);
    r[2] = (short)f2bf(v0.z); r[3] = (short)f2bf(v0.w);
    r[4] = (short)f2bf(v1.x); r[5] = (short)f2bf(v1.y);
    r[6] = (short)f2bf(v1.z); r[7] = (short)f2bf(v1.w);
    *(bf16x8*)d = r;
}

// ---------------------------------------------------------------------------
// bf16 MFMA GEMM, 2-phase double-buffered, BK=32, counted vmcnt(4).
// C[M,N] = A[M,K] * B[N,K]^T, fp32 out (store, or atomicAdd when SPLITK>1).
// 128x128 tile, 4 waves (2x2) of 64x64. LDS 32 KB total -> 4-5 blocks/CU;
// split-K enlarges the grid so 4 blocks/CU are actually available (staging
// rate scales with co-resident blocks: 10 B/cy/CU at 2 blk -> target 15-20).
// LDS layout per buf: [4 kb][128 row][8 elem] -> SQ_LDS_BANK_CONFLICT == 0.
// ---------------------------------------------------------------------------
__device__ __forceinline__ void stage_tile(const ushort_t* __restrict__ A,
                                           const ushort_t* __restrict__ B,
                                           ushort_t* As, ushort_t* Bs,
                                           int m0, int n0, int K, int k0, int tid)
{
#pragma unroll
    for (int j = 0; j < 2; j++) {
        const int c   = j * 256 + tid;   // 16B chunk index 0..511
        const int row = c & 127;
        const int kbi = c >> 7;          // 0..3
        __builtin_amdgcn_global_load_lds(
            (const __attribute__((address_space(1))) uint_t*)(A + (size_t)(m0 + row) * K + k0 + kbi * 8),
            (__attribute__((address_space(3))) uint_t*)((char*)As + c * 16), 16, 0, 0);
        __builtin_amdgcn_global_load_lds(
            (const __attribute__((address_space(1))) uint_t*)(B + (size_t)(n0 + row) * K + k0 + kbi * 8),
            (__attribute__((address_space(3))) uint_t*)((char*)Bs + c * 16), 16, 0, 0);
    }
}

template<int SPLITK>
__global__ __launch_bounds__(256)
void gemm_bf16(const ushort_t* __restrict__ A,
               const ushort_t* __restrict__ B,
               float* __restrict__ C, int M, int N, int K)
{
    __shared__ ushort_t As[2][4096];   // [buf][kb*1024 + row*8 + e], 8 KB each
    __shared__ ushort_t Bs[2][4096];

    const int tid  = threadIdx.x;
    const int wid  = tid >> 6;
    const int lane = tid & 63;
    const int m0 = blockIdx.x * 128;
    const int n0 = blockIdx.y * 128;
    const int kcnt  = (SPLITK > 1) ? (K / SPLITK) : K;
    const int kbase = (SPLITK > 1) ? blockIdx.z * kcnt : 0;
    const int NT = kcnt / 32;
    const int wr = (wid >> 1) * 64;
    const int wc = (wid & 1) * 64;
    const int lr = lane & 15;
    const int kbq = lane >> 4;           // 0..3

    f32x4 acc[4][4];
#pragma unroll
    for (int m = 0; m < 4; m++)
#pragma unroll
        for (int n = 0; n < 4; n++)
            acc[m][n] = (f32x4){0.f, 0.f, 0.f, 0.f};

    stage_tile(A, B, As[0], Bs[0], m0, n0, K, kbase, tid);

    for (int t = 0; t < NT; t++) {
        const int cur = t & 1;
        if (t + 1 < NT) {
            stage_tile(A, B, As[cur ^ 1], Bs[cur ^ 1], m0, n0, K, kbase + (t + 1) * 32, tid);
            asm volatile("s_waitcnt vmcnt(4)" ::: "memory");   // cur buf's 4 loads done
        } else {
            asm volatile("s_waitcnt vmcnt(0)" ::: "memory");
        }
        __builtin_amdgcn_s_barrier();          // all waves' cur loads landed
        __builtin_amdgcn_sched_barrier(0);

        bf16x8 af[4], bfr[4];
#pragma unroll
        for (int m = 0; m < 4; m++)
            af[m] = *(const bf16x8*)&As[cur][(kbq * 128 + wr + m * 16 + lr) * 8];
#pragma unroll
        for (int n = 0; n < 4; n++)
            bfr[n] = *(const bf16x8*)&Bs[cur][(kbq * 128 + wc + n * 16 + lr) * 8];
#pragma unroll
        for (int m = 0; m < 4; m++)
#pragma unroll
            for (int n = 0; n < 4; n++)
                acc[m][n] = __builtin_amdgcn_mfma_f32_16x16x32_bf16(af[m], bfr[n], acc[m][n], 0, 0, 0);

        __builtin_amdgcn_sched_barrier(0);
        __builtin_amdgcn_s_barrier();          // reads done; next iter may overwrite
    }

    const int er = (lane >> 4) * 4;
    const int ec = lane & 15;
#pragma unroll
    for (int m = 0; m < 4; m++) {
        const int grow = m0 + wr + m * 16 + er;
#pragma unroll
        for (int n = 0; n < 4; n++) {
            const int gcol = n0 + wc + n * 16 + ec;
#pragma unroll
            for (int r = 0; r < 4; r++) {
                if (SPLITK > 1)
                    atomicAdd(&C[(size_t)(grow + r) * N + gcol], acc[m][n][r]);
                else
                    C[(size_t)(grow + r) * N + gcol] = acc[m][n][r];
            }
        }
    }
}

// ---------------------------------------------------------------------------
// 64x64 tile fp32 GEMM, optional split-K (atomicAdd) / bias+softplus epilogue
// ---------------------------------------------------------------------------
template<int EPI, int SPLITK>
__global__ __launch_bounds__(256)
void gemm64(const float* __restrict__ A, int lda,
            const float* __restrict__ B, int ldb,
            float* C, int ldc,
            const float* __restrict__ bias,
            int M, int N, int K, int KC)
{
    __shared__ float As[16][68];
    __shared__ float Bs[16][68];
    const int tid = threadIdx.x;
    const int m0 = blockIdx.x * 64;
    const int n0 = blockIdx.y * 64;
    const int kbeg = SPLITK ? blockIdx.z * KC : 0;
    const int kend = SPLITK ? min(K, kbeg + KC) : K;
    const int lr = tid >> 2;
    const int lq = (tid & 3) * 4;
    const int tm = tid >> 4;
    const int tn = tid & 15;

    float acc[4][4];
#pragma unroll
    for (int i = 0; i < 4; i++)
#pragma unroll
        for (int j = 0; j < 4; j++) acc[i][j] = 0.f;

    const bool am = (m0 + lr) < M;
    const bool bn = (n0 + lr) < N;
    const float* Arow = A + (size_t)(m0 + lr) * lda;
    const float* Brow = B + (size_t)(n0 + lr) * ldb;

    for (int k0 = kbeg; k0 < kend; k0 += 16) {
        float4 va = am ? *(const float4*)(Arow + k0 + lq) : make_float4(0,0,0,0);
        float4 vb = bn ? *(const float4*)(Brow + k0 + lq) : make_float4(0,0,0,0);
        __syncthreads();
        As[lq+0][lr]=va.x; As[lq+1][lr]=va.y; As[lq+2][lr]=va.z; As[lq+3][lr]=va.w;
        Bs[lq+0][lr]=vb.x; Bs[lq+1][lr]=vb.y; Bs[lq+2][lr]=vb.z; Bs[lq+3][lr]=vb.w;
        __syncthreads();
#pragma unroll
        for (int kk = 0; kk < 16; kk++) {
            float a_[4], b_[4];
#pragma unroll
            for (int i = 0; i < 4; i++) { a_[i] = As[kk][tm*4+i]; b_[i] = Bs[kk][tn*4+i]; }
#pragma unroll
            for (int i = 0; i < 4; i++)
#pragma unroll
                for (int j = 0; j < 4; j++)
                    acc[i][j] = fmaf(a_[i], b_[j], acc[i][j]);
        }
    }

#pragma unroll
    for (int i = 0; i < 4; i++) {
        int m = m0 + tm*4 + i;
        if (m >= M) continue;
#pragma unroll
        for (int j = 0; j < 4; j++) {
            int n = n0 + tn*4 + j;
            if (n >= N) continue;
            float c = acc[i][j];
            if (SPLITK) {
                atomicAdd(&C[(size_t)m * ldc + n], c);
            } else {
                if (EPI == 1) {
                    c += bias[n];
                    c = (c > 20.f) ? c : log1pf(__expf(c));
                }
                C[(size_t)m * ldc + n] = c;
            }
        }
    }
}

// ---------------------------------------------------------------------------
// Depthwise causal conv (width 4) + bias + SiLU.
// ---------------------------------------------------------------------------
__global__ __launch_bounds__(256)
void conv_silu_kernel(const float* __restrict__ xz,
                      const float* __restrict__ conv_w,
                      const float* __restrict__ conv_b,
                      float* __restrict__ xc)
{
    int idx = blockIdx.x * 256 + threadIdx.x;
    if (idx >= LSEQ * DINNER) return;
    int t = idx / DINNER;
    int d = idx - t * DINNER;
    float acc = conv_b[d];
#pragma unroll
    for (int j = 0; j < 4; j++) {
        int tt = t - 3 + j;
        if (tt >= 0) acc = fmaf(conv_w[d*4 + j], xz[(size_t)tt * (2*DINNER) + d], acc);
    }
    xc[idx] = siluf(acc);
}

// ---------------------------------------------------------------------------
// Chunked parallel selective scan, lane-owns-channel layout.
// ---------------------------------------------------------------------------
__global__ __launch_bounds__(256)
void scan_phase1(const float* __restrict__ dtm,
                 const float* __restrict__ xdbl,
                 const float* __restrict__ xc,
                 const float* __restrict__ A_log,
                 float* __restrict__ Aprod, float* __restrict__ hend)
{
    __shared__ float Bs[CL][16];
    const int tid = threadIdx.x;
    const int d = blockIdx.x * 256 + tid;
    const int c = blockIdx.y;
    const int t0 = c * CL;

    {
        int t = tid >> 3, n = (tid * 2) & 15;
        float2 v = *(const float2*)&xdbl[(size_t)(t0 + t) * XCOLS + DTRANK + n];
        Bs[t][n] = v.x; Bs[t][n + 1] = v.y;
    }

    float a[16];
#pragma unroll
    for (int q = 0; q < 4; q++) {
        f32x4 v = *(const f32x4*)&A_log[(size_t)d * DSTATE + q * 4];
#pragma unroll
        for (int j = 0; j < 4; j++) a[q * 4 + j] = -__expf(v[j]);
    }
    float h[16];
#pragma unroll
    for (int n = 0; n < 16; n++) h[n] = 0.f;
    float sdt = 0.f;

    __syncthreads();

    float dtv = dtm[(size_t)t0 * DINNER + d];
    float xv  = xc[(size_t)t0 * DINNER + d];
    for (int tt = 0; tt < CL; tt++) {
        int tn_ = t0 + ((tt + 1 < CL) ? tt + 1 : tt);
        float dtv_n = dtm[(size_t)tn_ * DINNER + d];
        float xv_n  = xc[(size_t)tn_ * DINNER + d];

        f32x4 Bq[4];
#pragma unroll
        for (int q = 0; q < 4; q++) Bq[q] = *(const f32x4*)&Bs[tt][q * 4];
        float dtx = dtv * xv;
        sdt += dtv;
#pragma unroll
        for (int n = 0; n < 16; n++) {
            float e = __expf(dtv * a[n]);
            h[n] = fmaf(e, h[n], dtx * Bq[n >> 2][n & 3]);
        }
        dtv = dtv_n; xv = xv_n;
    }

#pragma unroll
    for (int n = 0; n < 16; n++) {
        const size_t k = (size_t)c * SSTATE + (size_t)n * DINNER + d;
        hend[k]  = h[n];
        Aprod[k] = __expf(a[n] * sdt);
    }
}

__global__ __launch_bounds__(256)
void scan_phase2(const float* __restrict__ Aprod, float* __restrict__ hend)
{
    const int idx = blockIdx.x * 256 + threadIdx.x;
    float carry = 0.f;
#pragma unroll
    for (int c = 0; c < NC; c++) {
        const size_t k = (size_t)c * SSTATE + idx;
        float oh = hend[k];
        float oA = Aprod[k];
        hend[k] = carry;
        carry = fmaf(oA, carry, oh);
    }
}

__global__ __launch_bounds__(256)
void scan_phase3(const float* __restrict__ dtm,
                 const float* __restrict__ xdbl,
                 const float* __restrict__ xc,
                 const float* __restrict__ A_log,
                 const float* __restrict__ Dp,
                 const float* __restrict__ xz,
                 const float* __restrict__ hinit,
                 ushort_t* __restrict__ yb)
{
    __shared__ float Bs[CL][16];
    __shared__ float Cs[CL][16];
    const int tid = threadIdx.x;
    const int d = blockIdx.x * 256 + tid;
    const int c = blockIdx.y;
    const int t0 = c * CL;

    {
        int r = tid & 127;
        int t = r >> 2, n = (r * 4) & 15;
        const float* src = &xdbl[(size_t)(t0 + t) * XCOLS + DTRANK + ((tid < 128) ? 0 : DSTATE) + n];
        float4 v = *(const float4*)src;
        float* dst = (tid < 128) ? &Bs[t][n] : &Cs[t][n];
        dst[0] = v.x; dst[1] = v.y; dst[2] = v.z; dst[3] = v.w;
    }

    float a[16];
#pragma unroll
    for (int q = 0; q < 4; q++) {
        f32x4 v = *(const f32x4*)&A_log[(size_t)d * DSTATE + q * 4];
#pragma unroll
        for (int j = 0; j < 4; j++) a[q * 4 + j] = -__expf(v[j]);
    }
    const float Dv = Dp[d];
    float h[16];
#pragma unroll
    for (int n = 0; n < 16; n++)
        h[n] = hinit[(size_t)c * SSTATE + (size_t)n * DINNER + d];

    __syncthreads();

    float dtv = dtm[(size_t)t0 * DINNER + d];
    float xv  = xc[(size_t)t0 * DINNER + d];
    for (int tt = 0; tt < CL; tt++) {
        const int t = t0 + tt;
        int tn_ = t0 + ((tt + 1 < CL) ? tt + 1 : tt);
        float dtv_n = dtm[(size_t)tn_ * DINNER + d];
        float xv_n  = xc[(size_t)tn_ * DINNER + d];
        float zv    = xz[(size_t)t * (2 * DINNER) + DINNER + d];

        f32x4 Bq[4], Cq[4];
#pragma unroll
        for (int q = 0; q < 4; q++) {
            Bq[q] = *(const f32x4*)&Bs[tt][q * 4];
            Cq[q] = *(const f32x4*)&Cs[tt][q * 4];
        }
        float dtx = dtv * xv;
        float y = 0.f;
#pragma unroll
        for (int n = 0; n < 16; n++) {
            float e = __expf(dtv * a[n]);
            h[n] = fmaf(e, h[n], dtx * Bq[n >> 2][n & 3]);
            y = fmaf(h[n], Cq[n >> 2][n & 3], y);
        }
        yb[(size_t)t * DINNER + d] = f2bf((y + Dv * xv) * siluf(zv));
        dtv = dtv_n; xv = xv_n;
    }
}

// ---------------------------------------------------------------------------
extern "C" void kernel_launch(void* const* d_in, const int* in_sizes, int n_in,
                              void* d_out, int out_size, void* d_ws, size_t ws_size,
                              hipStream_t stream)
{
    const float* x      = (const float*)d_in[0];
    const float* W_in   = (const float*)d_in[1];
    const float* conv_w = (const float*)d_in[2];
    const float* conv_b = (const float*)d_in[3];
    const float* W_x    = (const float*)d_in[4];
    const float* W_dt   = (const float*)d_in[5];
    const float* b_dt   = (const float*)d_in[6];
    const float* A_log  = (const float*)d_in[7];
    const float* D_par  = (const float*)d_in[8];
    const float* W_out  = (const float*)d_in[9];
    float* out = (float*)d_out;
    float* ws  = (float*)d_ws;

    float* xz    = ws;                                   // 2048*4096 f32
    float* xc    = xz   + (size_t)LSEQ * 2 * DINNER;     // 2048*2048 f32
    float* xdbl  = xc   + (size_t)LSEQ * DINNER;         // 2048*96  f32
    float* dtm   = xdbl + (size_t)LSEQ * XCOLS;          // 2048*2048 f32
    float* Aprod = dtm  + (size_t)LSEQ * DINNER;         // NC*SSTATE f32
    float* hend  = Aprod + (size_t)NC * SSTATE;          // NC*SSTATE f32
    ushort_t* xb  = (ushort_t*)(hend + (size_t)NC * SSTATE);   // 2048*1024 bf16
    ushort_t* Wib = xb  + (size_t)LSEQ * DMODEL;               // 4096*1024 bf16
    ushort_t* Wob = Wib + (size_t)(2*DINNER) * DMODEL;         // 1024*2048 bf16
    ushort_t* yb  = Wob + (size_t)DMODEL * DINNER;             // 2048*2048 bf16

    // 0a. zero the split-K accumulation targets up front
    hipMemsetAsync(xz, 0, (size_t)LSEQ * 2 * DINNER * sizeof(float), stream);
    hipMemsetAsync(xdbl, 0, (size_t)LSEQ * XCOLS * sizeof(float), stream);
    hipMemsetAsync(out, 0, (size_t)LSEQ * DMODEL * sizeof(float), stream);

    // 0b. fused casts to bf16 (x, W_in, W_out)
    {
        int c0 = LSEQ * DMODEL, c1 = 2 * DINNER * DMODEL, c2 = DMODEL * DINNER;
        hipLaunchKernelGGL(cast3_kernel, dim3(((c0 + c1 + c2) / 8) / 256), dim3(256), 0, stream,
                           x, xb, c0, W_in, Wib, c1, W_out, Wob, c2);
    }

    // 1. in_proj: xz = x @ W_in^T   (2048 x 4096), bf16 MFMA, SK=2 -> 1024 blocks
    hipLaunchKernelGGL((gemm_bf16<2>), dim3(LSEQ/128, (2*DINNER)/128, 2), dim3(256), 0, stream,
                       xb, Wib, xz, LSEQ, 2*DINNER, DMODEL);

    // 2. depthwise conv + SiLU -> xc
    hipLaunchKernelGGL(conv_silu_kernel, dim3((LSEQ*DINNER)/256), dim3(256), 0, stream,
                       xz, conv_w, conv_b, xc);

    // 3. x_dbl = xc @ W_x^T  (2048 x 96), fp32, split-K over 8 chunks
    hipLaunchKernelGGL((gemm64<0,1>), dim3(LSEQ/64, 2, 8), dim3(256), 0, stream,
                       xc, DINNER, W_x, DINNER, xdbl, XCOLS, (const float*)nullptr,
                       LSEQ, XCOLS, DINNER, 256);

    // 4. dt = softplus(x_dbl[:, :64] @ W_dt^T + b_dt)  (2048 x 2048), fp32
    hipLaunchKernelGGL((gemm64<1,0>), dim3(LSEQ/64, DINNER/64, 1), dim3(256), 0, stream,
                       xdbl, XCOLS, W_dt, DTRANK, dtm, DINNER, b_dt,
                       LSEQ, DINNER, DTRANK, 0);

    // 5. chunked parallel scan (lane-owns-channel); phase 3 writes bf16 y
    hipLaunchKernelGGL(scan_phase1, dim3(DINNER/256, NC), dim3(256), 0, stream,
                       dtm, xdbl, xc, A_log, Aprod, hend);
    hipLaunchKernelGGL(scan_phase2, dim3(SSTATE/256), dim3(256), 0, stream,
                       Aprod, hend);
    hipLaunchKernelGGL(scan_phase3, dim3(DINNER/256, NC), dim3(256), 0, stream,
                       dtm, xdbl, xc, A_log, D_par, xz, hend, yb);

    // 6. out = y @ W_out^T  (2048 x 1024), bf16 MFMA, SK=8 -> 1024 blocks
    hipLaunchKernelGGL((gemm_bf16<8>), dim3(LSEQ/128, DMODEL/128, 8), dim3(256), 0, stream,
                       yb, Wob, out, LSEQ, DMODEL, DINNER);
}

// Round 8
// 241.940 us; speedup vs baseline: 1.2215x; 1.2215x over previous
//
#include <hip/hip_runtime.h>
#include <math.h>

#define LSEQ   2048
#define DMODEL 1024
#define DINNER 2048
#define DSTATE 16
#define DTRANK 64
#define XCOLS  96   // dt_rank + 2*d_state
#define CL     32   // scan chunk length
#define NC     (LSEQ/CL)          // 64 chunks
#define SSTATE (DINNER*DSTATE)    // 32768 scalar recurrences

typedef __attribute__((ext_vector_type(8))) short bf16x8;
typedef __attribute__((ext_vector_type(4))) float f32x4;
typedef unsigned short ushort_t;
typedef unsigned int uint_t;

__device__ __forceinline__ float siluf(float v) { return v / (1.f + __expf(-v)); }

// RNE float -> bf16 bits (finite inputs)
__device__ __forceinline__ ushort_t f2bf(float f) {
    uint_t u = __float_as_uint(f);
    u += 0x7FFFu + ((u >> 16) & 1u);
    return (ushort_t)(u >> 16);
}

// ---------------------------------------------------------------------------
// fused f32 -> bf16 cast for 3 tensors, 8 elements/thread. sizes % 8 == 0.
// ---------------------------------------------------------------------------
__global__ __launch_bounds__(256)
void cast3_kernel(const float* __restrict__ s0, ushort_t* __restrict__ d0, int c0,
                  const float* __restrict__ s1, ushort_t* __restrict__ d1, int c1,
                  const float* __restrict__ s2, ushort_t* __restrict__ d2, int c2)
{
    int i = (blockIdx.x * 256 + threadIdx.x) * 8;
    const float* s; ushort_t* d;
    if (i < c0)           { s = s0 + i;            d = d0 + i; }
    else if (i < c0 + c1) { s = s1 + (i - c0);     d = d1 + (i - c0); }
    else if (i < c0 + c1 + c2) { s = s2 + (i - c0 - c1); d = d2 + (i - c0 - c1); }
    else return;
    float4 v0 = *(const float4*)s;
    float4 v1 = *(const float4*)(s + 4);
    bf16x8 r;
    r[0] = (short)f2bf(v0.x); r[1] = (short)f2bf(v0.y);
    r[2] = (short)f2bf(v0.z); r[3] = (short)f2bf(v0.w);
    r[4] = (short)f2bf(v1.x); r[5] = (short)f2bf(v1.y);
    r[6] = (short)f2bf(v1.z); r[7] = (short)f2bf(v1.w);
    *(bf16x8*)d = r;
}

// ---------------------------------------------------------------------------
// bf16 MFMA GEMM: 3-buffer LDS ring, depth-2 prefetch, counted vmcnt.
// C[M,N] = A[M,K] * B[N,K]^T, fp32 store (no atomics — r7 lesson).
// 128x128 tile, BK=32, 4 waves (2x2) of 64x64.
// LDS per buf: [4 kb][128 row][8 elem] (8 KB) -> SQ_LDS_BANK_CONFLICT == 0.
// Ring safety: stage(t+2) writes buf (t+2)%3 == (t-1)%3, last read at t-1,
// separated by t-1's end-of-iteration barrier.
// ---------------------------------------------------------------------------
__device__ __forceinline__ void stage_tile(const ushort_t* __restrict__ A,
                                           const ushort_t* __restrict__ B,
                                           ushort_t* As, ushort_t* Bs,
                                           int m0, int n0, int K, int k0, int tid)
{
#pragma unroll
    for (int j = 0; j < 2; j++) {
        const int c   = j * 256 + tid;   // 16B chunk index 0..511
        const int row = c & 127;
        const int kbi = c >> 7;          // 0..3
        __builtin_amdgcn_global_load_lds(
            (const __attribute__((address_space(1))) uint_t*)(A + (size_t)(m0 + row) * K + k0 + kbi * 8),
            (__attribute__((address_space(3))) uint_t*)((char*)As + c * 16), 16, 0, 0);
        __builtin_amdgcn_global_load_lds(
            (const __attribute__((address_space(1))) uint_t*)(B + (size_t)(n0 + row) * K + k0 + kbi * 8),
            (__attribute__((address_space(3))) uint_t*)((char*)Bs + c * 16), 16, 0, 0);
    }
}

__global__ __launch_bounds__(256)
void gemm_bf16(const ushort_t* __restrict__ A,
               const ushort_t* __restrict__ B,
               float* __restrict__ C, int M, int N, int K)
{
    __shared__ ushort_t As[3][4096];   // 3-buffer ring, 8 KB each
    __shared__ ushort_t Bs[3][4096];

    const int tid  = threadIdx.x;
    const int wid  = tid >> 6;
    const int lane = tid & 63;
    const int m0 = blockIdx.x * 128;
    const int n0 = blockIdx.y * 128;
    const int NT = K / 32;
    const int wr = (wid >> 1) * 64;
    const int wc = (wid & 1) * 64;
    const int lr = lane & 15;
    const int kbq = lane >> 4;           // 0..3

    f32x4 acc[4][4];
#pragma unroll
    for (int m = 0; m < 4; m++)
#pragma unroll
        for (int n = 0; n < 4; n++)
            acc[m][n] = (f32x4){0.f, 0.f, 0.f, 0.f};

    stage_tile(A, B, As[0], Bs[0], m0, n0, K, 0, tid);
    stage_tile(A, B, As[1], Bs[1], m0, n0, K, 32, tid);

    for (int t = 0; t < NT; t++) {
        const int cur = t % 3;
        if (t + 2 < NT) {
            stage_tile(A, B, As[(t + 2) % 3], Bs[(t + 2) % 3], m0, n0, K, (t + 2) * 32, tid);
            asm volatile("s_waitcnt vmcnt(8)" ::: "memory");   // stage(t) done; t+1,t+2 in flight
        } else if (t + 1 < NT) {
            asm volatile("s_waitcnt vmcnt(4)" ::: "memory");   // stage(t) done; t+1 in flight
        } else {
            asm volatile("s_waitcnt vmcnt(0)" ::: "memory");
        }
        __builtin_amdgcn_s_barrier();          // all waves' stage(t) loads landed
        __builtin_amdgcn_sched_barrier(0);

        bf16x8 af[4], bfr[4];
#pragma unroll
        for (int m = 0; m < 4; m++)
            af[m] = *(const bf16x8*)&As[cur][(kbq * 128 + wr + m * 16 + lr) * 8];
#pragma unroll
        for (int n = 0; n < 4; n++)
            bfr[n] = *(const bf16x8*)&Bs[cur][(kbq * 128 + wc + n * 16 + lr) * 8];
#pragma unroll
        for (int m = 0; m < 4; m++)
#pragma unroll
            for (int n = 0; n < 4; n++)
                acc[m][n] = __builtin_amdgcn_mfma_f32_16x16x32_bf16(af[m], bfr[n], acc[m][n], 0, 0, 0);

        __builtin_amdgcn_sched_barrier(0);
        __builtin_amdgcn_s_barrier();          // reads of buf cur done before its reuse
    }

    const int er = (lane >> 4) * 4;
    const int ec = lane & 15;
#pragma unroll
    for (int m = 0; m < 4; m++) {
        const int grow = m0 + wr + m * 16 + er;
#pragma unroll
        for (int n = 0; n < 4; n++) {
            const int gcol = n0 + wc + n * 16 + ec;
#pragma unroll
            for (int r = 0; r < 4; r++)
                C[(size_t)(grow + r) * N + gcol] = acc[m][n][r];
        }
    }
}

// ---------------------------------------------------------------------------
// 64x64 tile fp32 GEMM, optional split-K (atomicAdd) / bias+softplus epilogue
// (atomic split-K only used for the tiny 2048x96 output — 786 KB, harmless)
// ---------------------------------------------------------------------------
template<int EPI, int SPLITK>
__global__ __launch_bounds__(256)
void gemm64(const float* __restrict__ A, int lda,
            const float* __restrict__ B, int ldb,
            float* C, int ldc,
            const float* __restrict__ bias,
            int M, int N, int K, int KC)
{
    __shared__ float As[16][68];
    __shared__ float Bs[16][68];
    const int tid = threadIdx.x;
    const int m0 = blockIdx.x * 64;
    const int n0 = blockIdx.y * 64;
    const int kbeg = SPLITK ? blockIdx.z * KC : 0;
    const int kend = SPLITK ? min(K, kbeg + KC) : K;
    const int lr = tid >> 2;
    const int lq = (tid & 3) * 4;
    const int tm = tid >> 4;
    const int tn = tid & 15;

    float acc[4][4];
#pragma unroll
    for (int i = 0; i < 4; i++)
#pragma unroll
        for (int j = 0; j < 4; j++) acc[i][j] = 0.f;

    const bool am = (m0 + lr) < M;
    const bool bn = (n0 + lr) < N;
    const float* Arow = A + (size_t)(m0 + lr) * lda;
    const float* Brow = B + (size_t)(n0 + lr) * ldb;

    for (int k0 = kbeg; k0 < kend; k0 += 16) {
        float4 va = am ? *(const float4*)(Arow + k0 + lq) : make_float4(0,0,0,0);
        float4 vb = bn ? *(const float4*)(Brow + k0 + lq) : make_float4(0,0,0,0);
        __syncthreads();
        As[lq+0][lr]=va.x; As[lq+1][lr]=va.y; As[lq+2][lr]=va.z; As[lq+3][lr]=va.w;
        Bs[lq+0][lr]=vb.x; Bs[lq+1][lr]=vb.y; Bs[lq+2][lr]=vb.z; Bs[lq+3][lr]=vb.w;
        __syncthreads();
#pragma unroll
        for (int kk = 0; kk < 16; kk++) {
            float a_[4], b_[4];
#pragma unroll
            for (int i = 0; i < 4; i++) { a_[i] = As[kk][tm*4+i]; b_[i] = Bs[kk][tn*4+i]; }
#pragma unroll
            for (int i = 0; i < 4; i++)
#pragma unroll
                for (int j = 0; j < 4; j++)
                    acc[i][j] = fmaf(a_[i], b_[j], acc[i][j]);
        }
    }

#pragma unroll
    for (int i = 0; i < 4; i++) {
        int m = m0 + tm*4 + i;
        if (m >= M) continue;
#pragma unroll
        for (int j = 0; j < 4; j++) {
            int n = n0 + tn*4 + j;
            if (n >= N) continue;
            float c = acc[i][j];
            if (SPLITK) {
                atomicAdd(&C[(size_t)m * ldc + n], c);
            } else {
                if (EPI == 1) {
                    c += bias[n];
                    c = (c > 20.f) ? c : log1pf(__expf(c));
                }
                C[(size_t)m * ldc + n] = c;
            }
        }
    }
}

// ---------------------------------------------------------------------------
// Depthwise causal conv (width 4) + bias + SiLU.
// ---------------------------------------------------------------------------
__global__ __launch_bounds__(256)
void conv_silu_kernel(const float* __restrict__ xz,
                      const float* __restrict__ conv_w,
                      const float* __restrict__ conv_b,
                      float* __restrict__ xc)
{
    int idx = blockIdx.x * 256 + threadIdx.x;
    if (idx >= LSEQ * DINNER) return;
    int t = idx / DINNER;
    int d = idx - t * DINNER;
    float acc = conv_b[d];
#pragma unroll
    for (int j = 0; j < 4; j++) {
        int tt = t - 3 + j;
        if (tt >= 0) acc = fmaf(conv_w[d*4 + j], xz[(size_t)tt * (2*DINNER) + d], acc);
    }
    xc[idx] = siluf(acc);
}

// ---------------------------------------------------------------------------
// Chunked parallel selective scan, lane-owns-channel layout.
// ---------------------------------------------------------------------------
__global__ __launch_bounds__(256)
void scan_phase1(const float* __restrict__ dtm,
                 const float* __restrict__ xdbl,
                 const float* __restrict__ xc,
                 const float* __restrict__ A_log,
                 float* __restrict__ Aprod, float* __restrict__ hend)
{
    __shared__ float Bs[CL][16];
    const int tid = threadIdx.x;
    const int d = blockIdx.x * 256 + tid;
    const int c = blockIdx.y;
    const int t0 = c * CL;

    {
        int t = tid >> 3, n = (tid * 2) & 15;
        float2 v = *(const float2*)&xdbl[(size_t)(t0 + t) * XCOLS + DTRANK + n];
        Bs[t][n] = v.x; Bs[t][n + 1] = v.y;
    }

    float a[16];
#pragma unroll
    for (int q = 0; q < 4; q++) {
        f32x4 v = *(const f32x4*)&A_log[(size_t)d * DSTATE + q * 4];
#pragma unroll
        for (int j = 0; j < 4; j++) a[q * 4 + j] = -__expf(v[j]);
    }
    float h[16];
#pragma unroll
    for (int n = 0; n < 16; n++) h[n] = 0.f;
    float sdt = 0.f;

    __syncthreads();

    float dtv = dtm[(size_t)t0 * DINNER + d];
    float xv  = xc[(size_t)t0 * DINNER + d];
    for (int tt = 0; tt < CL; tt++) {
        int tn_ = t0 + ((tt + 1 < CL) ? tt + 1 : tt);
        float dtv_n = dtm[(size_t)tn_ * DINNER + d];
        float xv_n  = xc[(size_t)tn_ * DINNER + d];

        f32x4 Bq[4];
#pragma unroll
        for (int q = 0; q < 4; q++) Bq[q] = *(const f32x4*)&Bs[tt][q * 4];
        float dtx = dtv * xv;
        sdt += dtv;
#pragma unroll
        for (int n = 0; n < 16; n++) {
            float e = __expf(dtv * a[n]);
            h[n] = fmaf(e, h[n], dtx * Bq[n >> 2][n & 3]);
        }
        dtv = dtv_n; xv = xv_n;
    }

#pragma unroll
    for (int n = 0; n < 16; n++) {
        const size_t k = (size_t)c * SSTATE + (size_t)n * DINNER + d;
        hend[k]  = h[n];
        Aprod[k] = __expf(a[n] * sdt);
    }
}

__global__ __launch_bounds__(256)
void scan_phase2(const float* __restrict__ Aprod, float* __restrict__ hend)
{
    const int idx = blockIdx.x * 256 + threadIdx.x;
    float carry = 0.f;
#pragma unroll
    for (int c = 0; c < NC; c++) {
        const size_t k = (size_t)c * SSTATE + idx;
        float oh = hend[k];
        float oA = Aprod[k];
        hend[k] = carry;
        carry = fmaf(oA, carry, oh);
    }
}

__global__ __launch_bounds__(256)
void scan_phase3(const float* __restrict__ dtm,
                 const float* __restrict__ xdbl,
                 const float* __restrict__ xc,
                 const float* __restrict__ A_log,
                 const float* __restrict__ Dp,
                 const float* __restrict__ xz,
                 const float* __restrict__ hinit,
                 ushort_t* __restrict__ yb)
{
    __shared__ float Bs[CL][16];
    __shared__ float Cs[CL][16];
    const int tid = threadIdx.x;
    const int d = blockIdx.x * 256 + tid;
    const int c = blockIdx.y;
    const int t0 = c * CL;

    {
        int r = tid & 127;
        int t = r >> 2, n = (r * 4) & 15;
        const float* src = &xdbl[(size_t)(t0 + t) * XCOLS + DTRANK + ((tid < 128) ? 0 : DSTATE) + n];
        float4 v = *(const float4*)src;
        float* dst = (tid < 128) ? &Bs[t][n] : &Cs[t][n];
        dst[0] = v.x; dst[1] = v.y; dst[2] = v.z; dst[3] = v.w;
    }

    float a[16];
#pragma unroll
    for (int q = 0; q < 4; q++) {
        f32x4 v = *(const f32x4*)&A_log[(size_t)d * DSTATE + q * 4];
#pragma unroll
        for (int j = 0; j < 4; j++) a[q * 4 + j] = -__expf(v[j]);
    }
    const float Dv = Dp[d];
    float h[16];
#pragma unroll
    for (int n = 0; n < 16; n++)
        h[n] = hinit[(size_t)c * SSTATE + (size_t)n * DINNER + d];

    __syncthreads();

    float dtv = dtm[(size_t)t0 * DINNER + d];
    float xv  = xc[(size_t)t0 * DINNER + d];
    for (int tt = 0; tt < CL; tt++) {
        const int t = t0 + tt;
        int tn_ = t0 + ((tt + 1 < CL) ? tt + 1 : tt);
        float dtv_n = dtm[(size_t)tn_ * DINNER + d];
        float xv_n  = xc[(size_t)tn_ * DINNER + d];
        float zv    = xz[(size_t)t * (2 * DINNER) + DINNER + d];

        f32x4 Bq[4], Cq[4];
#pragma unroll
        for (int q = 0; q < 4; q++) {
            Bq[q] = *(const f32x4*)&Bs[tt][q * 4];
            Cq[q] = *(const f32x4*)&Cs[tt][q * 4];
        }
        float dtx = dtv * xv;
        float y = 0.f;
#pragma unroll
        for (int n = 0; n < 16; n++) {
            float e = __expf(dtv * a[n]);
            h[n] = fmaf(e, h[n], dtx * Bq[n >> 2][n & 3]);
            y = fmaf(h[n], Cq[n >> 2][n & 3], y);
        }
        yb[(size_t)t * DINNER + d] = f2bf((y + Dv * xv) * siluf(zv));
        dtv = dtv_n; xv = xv_n;
    }
}

// ---------------------------------------------------------------------------
extern "C" void kernel_launch(void* const* d_in, const int* in_sizes, int n_in,
                              void* d_out, int out_size, void* d_ws, size_t ws_size,
                              hipStream_t stream)
{
    const float* x      = (const float*)d_in[0];
    const float* W_in   = (const float*)d_in[1];
    const float* conv_w = (const float*)d_in[2];
    const float* conv_b = (const float*)d_in[3];
    const float* W_x    = (const float*)d_in[4];
    const float* W_dt   = (const float*)d_in[5];
    const float* b_dt   = (const float*)d_in[6];
    const float* A_log  = (const float*)d_in[7];
    const float* D_par  = (const float*)d_in[8];
    const float* W_out  = (const float*)d_in[9];
    float* out = (float*)d_out;
    float* ws  = (float*)d_ws;

    float* xz    = ws;                                   // 2048*4096 f32
    float* xc    = xz   + (size_t)LSEQ * 2 * DINNER;     // 2048*2048 f32
    float* xdbl  = xc   + (size_t)LSEQ * DINNER;         // 2048*96  f32
    float* dtm   = xdbl + (size_t)LSEQ * XCOLS;          // 2048*2048 f32
    float* Aprod = dtm  + (size_t)LSEQ * DINNER;         // NC*SSTATE f32
    float* hend  = Aprod + (size_t)NC * SSTATE;          // NC*SSTATE f32
    ushort_t* xb  = (ushort_t*)(hend + (size_t)NC * SSTATE);   // 2048*1024 bf16
    ushort_t* Wib = xb  + (size_t)LSEQ * DMODEL;               // 4096*1024 bf16
    ushort_t* Wob = Wib + (size_t)(2*DINNER) * DMODEL;         // 1024*2048 bf16
    ushort_t* yb  = Wob + (size_t)DMODEL * DINNER;             // 2048*2048 bf16

    // 0. fused casts to bf16 (x, W_in, W_out)
    {
        int c0 = LSEQ * DMODEL, c1 = 2 * DINNER * DMODEL, c2 = DMODEL * DINNER;
        hipLaunchKernelGGL(cast3_kernel, dim3(((c0 + c1 + c2) / 8) / 256), dim3(256), 0, stream,
                           x, xb, c0, W_in, Wib, c1, W_out, Wob, c2);
    }

    // 1. in_proj: xz = x @ W_in^T  (2048 x 4096), bf16 MFMA, ring-3 depth-2
    hipLaunchKernelGGL(gemm_bf16, dim3(LSEQ/128, (2*DINNER)/128), dim3(256), 0, stream,
                       xb, Wib, xz, LSEQ, 2*DINNER, DMODEL);

    // 2. depthwise conv + SiLU -> xc
    hipLaunchKernelGGL(conv_silu_kernel, dim3((LSEQ*DINNER)/256), dim3(256), 0, stream,
                       xz, conv_w, conv_b, xc);

    // 3. x_dbl = xc @ W_x^T  (2048 x 96), fp32, split-K over 8 chunks
    hipMemsetAsync(xdbl, 0, (size_t)LSEQ * XCOLS * sizeof(float), stream);
    hipLaunchKernelGGL((gemm64<0,1>), dim3(LSEQ/64, 2, 8), dim3(256), 0, stream,
                       xc, DINNER, W_x, DINNER, xdbl, XCOLS, (const float*)nullptr,
                       LSEQ, XCOLS, DINNER, 256);

    // 4. dt = softplus(x_dbl[:, :64] @ W_dt^T + b_dt)  (2048 x 2048), fp32
    hipLaunchKernelGGL((gemm64<1,0>), dim3(LSEQ/64, DINNER/64, 1), dim3(256), 0, stream,
                       xdbl, XCOLS, W_dt, DTRANK, dtm, DINNER, b_dt,
                       LSEQ, DINNER, DTRANK, 0);

    // 5. chunked parallel scan (lane-owns-channel); phase 3 writes bf16 y
    hipLaunchKernelGGL(scan_phase1, dim3(DINNER/256, NC), dim3(256), 0, stream,
                       dtm, xdbl, xc, A_log, Aprod, hend);
    hipLaunchKernelGGL(scan_phase2, dim3(SSTATE/256), dim3(256), 0, stream,
                       Aprod, hend);
    hipLaunchKernelGGL(scan_phase3, dim3(DINNER/256, NC), dim3(256), 0, stream,
                       dtm, xdbl, xc, A_log, D_par, xz, hend, yb);

    // 6. out = y @ W_out^T  (2048 x 1024), bf16 MFMA, ring-3 depth-2
    hipLaunchKernelGGL(gemm_bf16, dim3(LSEQ/128, DMODEL/128), dim3(256), 0, stream,
                       yb, Wob, out, LSEQ, DMODEL, DINNER);
}

// Round 9
// 221.870 us; speedup vs baseline: 1.3320x; 1.0905x over previous
//
#include <hip/hip_runtime.h>
#include <math.h>

#define LSEQ   2048
#define DMODEL 1024
#define DINNER 2048
#define DSTATE 16
#define DTRANK 64
#define XCOLS  96   // dt_rank + 2*d_state
#define CL     32   // scan chunk length
#define NC     (LSEQ/CL)          // 64 chunks
#define SSTATE (DINNER*DSTATE)    // 32768 scalar recurrences

typedef __attribute__((ext_vector_type(8))) short bf16x8;
typedef __attribute__((ext_vector_type(4))) float f32x4;
typedef unsigned short ushort_t;
typedef unsigned int uint_t;

__device__ __forceinline__ float siluf(float v) { return v / (1.f + __expf(-v)); }

// RNE float -> bf16 bits (finite inputs)
__device__ __forceinline__ ushort_t f2bf(float f) {
    uint_t u = __float_as_uint(f);
    u += 0x7FFFu + ((u >> 16) & 1u);
    return (ushort_t)(u >> 16);
}

__device__ __forceinline__ bf16x8 cvt8(float4 lo, float4 hi) {
    bf16x8 r;
    r[0] = (short)f2bf(lo.x); r[1] = (short)f2bf(lo.y);
    r[2] = (short)f2bf(lo.z); r[3] = (short)f2bf(lo.w);
    r[4] = (short)f2bf(hi.x); r[5] = (short)f2bf(hi.y);
    r[6] = (short)f2bf(hi.z); r[7] = (short)f2bf(hi.w);
    return r;
}

// ---------------------------------------------------------------------------
// fused f32 -> bf16 cast for 5 tensors, 8 elements/thread. sizes % 8 == 0.
// ---------------------------------------------------------------------------
__global__ __launch_bounds__(256)
void cast5_kernel(const float* __restrict__ s0, ushort_t* __restrict__ d0, int c0,
                  const float* __restrict__ s1, ushort_t* __restrict__ d1, int c1,
                  const float* __restrict__ s2, ushort_t* __restrict__ d2, int c2,
                  const float* __restrict__ s3, ushort_t* __restrict__ d3, int c3,
                  const float* __restrict__ s4, ushort_t* __restrict__ d4, int c4)
{
    int i = (blockIdx.x * 256 + threadIdx.x) * 8;
    const float* s; ushort_t* d;
    if (i < c0)                { s = s0 + i;                  d = d0 + i; }
    else if (i < c0+c1)        { s = s1 + (i-c0);             d = d1 + (i-c0); }
    else if (i < c0+c1+c2)     { s = s2 + (i-c0-c1);          d = d2 + (i-c0-c1); }
    else if (i < c0+c1+c2+c3)  { s = s3 + (i-c0-c1-c2);       d = d3 + (i-c0-c1-c2); }
    else if (i < c0+c1+c2+c3+c4) { s = s4 + (i-c0-c1-c2-c3);  d = d4 + (i-c0-c1-c2-c3); }
    else return;
    *(bf16x8*)d = cvt8(*(const float4*)s, *(const float4*)(s + 4));
}

// ---------------------------------------------------------------------------
// bf16 MFMA GEMM — r5-exact structure (measured best: 43.6 us at these shapes).
// 2-phase double-buffered, BK=32, counted vmcnt(4).
// C[M,N] = A[M,K] * B[N,K]^T, fp32 store.
// 128x128 tile, 4 waves (2x2) of 64x64.
// LDS per buf: [4 kb][128 row][8 elem] -> SQ_LDS_BANK_CONFLICT == 0.
// ---------------------------------------------------------------------------
__device__ __forceinline__ void stage_tile(const ushort_t* __restrict__ A,
                                           const ushort_t* __restrict__ B,
                                           ushort_t* As, ushort_t* Bs,
                                           int m0, int n0, int K, int k0, int tid)
{
#pragma unroll
    for (int j = 0; j < 2; j++) {
        const int c   = j * 256 + tid;   // 16B chunk index 0..511
        const int row = c & 127;
        const int kbi = c >> 7;          // 0..3
        __builtin_amdgcn_global_load_lds(
            (const __attribute__((address_space(1))) uint_t*)(A + (size_t)(m0 + row) * K + k0 + kbi * 8),
            (__attribute__((address_space(3))) uint_t*)((char*)As + c * 16), 16, 0, 0);
        __builtin_amdgcn_global_load_lds(
            (const __attribute__((address_space(1))) uint_t*)(B + (size_t)(n0 + row) * K + k0 + kbi * 8),
            (__attribute__((address_space(3))) uint_t*)((char*)Bs + c * 16), 16, 0, 0);
    }
}

__global__ __launch_bounds__(256)
void gemm_bf16(const ushort_t* __restrict__ A,
               const ushort_t* __restrict__ B,
               float* __restrict__ C, int M, int N, int K)
{
    __shared__ ushort_t As[2][4096];
    __shared__ ushort_t Bs[2][4096];

    const int tid  = threadIdx.x;
    const int wid  = tid >> 6;
    const int lane = tid & 63;
    const int m0 = blockIdx.x * 128;
    const int n0 = blockIdx.y * 128;
    const int NT = K / 32;
    const int wr = (wid >> 1) * 64;
    const int wc = (wid & 1) * 64;
    const int lr = lane & 15;
    const int kbq = lane >> 4;

    f32x4 acc[4][4];
#pragma unroll
    for (int m = 0; m < 4; m++)
#pragma unroll
        for (int n = 0; n < 4; n++)
            acc[m][n] = (f32x4){0.f, 0.f, 0.f, 0.f};

    stage_tile(A, B, As[0], Bs[0], m0, n0, K, 0, tid);

    for (int t = 0; t < NT; t++) {
        const int cur = t & 1;
        if (t + 1 < NT) {
            stage_tile(A, B, As[cur ^ 1], Bs[cur ^ 1], m0, n0, K, (t + 1) * 32, tid);
            asm volatile("s_waitcnt vmcnt(4)" ::: "memory");
        } else {
            asm volatile("s_waitcnt vmcnt(0)" ::: "memory");
        }
        __builtin_amdgcn_s_barrier();
        __builtin_amdgcn_sched_barrier(0);

        bf16x8 af[4], bfr[4];
#pragma unroll
        for (int m = 0; m < 4; m++)
            af[m] = *(const bf16x8*)&As[cur][(kbq * 128 + wr + m * 16 + lr) * 8];
#pragma unroll
        for (int n = 0; n < 4; n++)
            bfr[n] = *(const bf16x8*)&Bs[cur][(kbq * 128 + wc + n * 16 + lr) * 8];
#pragma unroll
        for (int m = 0; m < 4; m++)
#pragma unroll
            for (int n = 0; n < 4; n++)
                acc[m][n] = __builtin_amdgcn_mfma_f32_16x16x32_bf16(af[m], bfr[n], acc[m][n], 0, 0, 0);

        __builtin_amdgcn_sched_barrier(0);
        __builtin_amdgcn_s_barrier();
    }

    const int er = (lane >> 4) * 4;
    const int ec = lane & 15;
#pragma unroll
    for (int m = 0; m < 4; m++) {
        const int grow = m0 + wr + m * 16 + er;
#pragma unroll
        for (int n = 0; n < 4; n++) {
            const int gcol = n0 + wc + n * 16 + ec;
#pragma unroll
            for (int r = 0; r < 4; r++)
                C[(size_t)(grow + r) * N + gcol] = acc[m][n][r];
        }
    }
}

// ---------------------------------------------------------------------------
// x_dbl GEMM: xdbl[2048][96] += xcb[2048][2048]b16 @ Wxb[96][2048]b16^T
// Barrier-free direct-fragment MFMA, split-K=16, fp32 atomic epilogue
// (output only 786 KB -> ~12 MB atomic traffic, safe per r7 lesson).
// Tile 128 x 96, waves 2x2 of 64x48, acc[4][3]. Grid (16, 1, 16).
// ---------------------------------------------------------------------------
__global__ __launch_bounds__(256)
void gemm_xdbl(const ushort_t* __restrict__ A,
               const ushort_t* __restrict__ B,
               float* __restrict__ Cout)
{
    const int tid = threadIdx.x, wid = tid >> 6, lane = tid & 63;
    const int m0 = blockIdx.x * 128;
    const int kbase = blockIdx.z * 128;
    const int wr = (wid >> 1) * 64;
    const int wc = (wid & 1) * 48;
    const int lr = lane & 15;
    const int kq = (lane >> 4) * 8;

    f32x4 acc[4][3];
#pragma unroll
    for (int m = 0; m < 4; m++)
#pragma unroll
        for (int n = 0; n < 3; n++)
            acc[m][n] = (f32x4){0.f, 0.f, 0.f, 0.f};

#pragma unroll
    for (int ks = 0; ks < 4; ks++) {
        const int k0 = kbase + ks * 32;
        bf16x8 af[4], bfr[3];
#pragma unroll
        for (int m = 0; m < 4; m++)
            af[m] = *(const bf16x8*)(A + (size_t)(m0 + wr + m * 16 + lr) * DINNER + k0 + kq);
#pragma unroll
        for (int n = 0; n < 3; n++)
            bfr[n] = *(const bf16x8*)(B + (size_t)(wc + n * 16 + lr) * DINNER + k0 + kq);
#pragma unroll
        for (int m = 0; m < 4; m++)
#pragma unroll
            for (int n = 0; n < 3; n++)
                acc[m][n] = __builtin_amdgcn_mfma_f32_16x16x32_bf16(af[m], bfr[n], acc[m][n], 0, 0, 0);
    }

    const int er = (lane >> 4) * 4;
    const int ec = lane & 15;
#pragma unroll
    for (int m = 0; m < 4; m++)
#pragma unroll
        for (int n = 0; n < 3; n++)
#pragma unroll
            for (int r = 0; r < 4; r++)
                atomicAdd(&Cout[(size_t)(m0 + wr + m * 16 + er + r) * XCOLS + wc + n * 16 + ec],
                          acc[m][n][r]);
}

// ---------------------------------------------------------------------------
// dt GEMM: dtm[2048][2048] = softplus(xdbl[:, :64] @ Wdtb[2048][64]^T + b_dt)
// Barrier-free direct-fragment MFMA, K=64 (2 steps), fp32 A cvt in-register.
// Tile 128x128, waves 2x2 of 64x64. Grid (16, 16).
// ---------------------------------------------------------------------------
__global__ __launch_bounds__(256)
void gemm_dt(const float* __restrict__ Axd,
             const ushort_t* __restrict__ Bw,
             const float* __restrict__ bias,
             float* __restrict__ dtm)
{
    const int tid = threadIdx.x, wid = tid >> 6, lane = tid & 63;
    const int m0 = blockIdx.x * 128;
    const int n0 = blockIdx.y * 128;
    const int wr = (wid >> 1) * 64;
    const int wc = (wid & 1) * 64;
    const int lr = lane & 15;
    const int kq = (lane >> 4) * 8;

    f32x4 acc[4][4];
#pragma unroll
    for (int m = 0; m < 4; m++)
#pragma unroll
        for (int n = 0; n < 4; n++)
            acc[m][n] = (f32x4){0.f, 0.f, 0.f, 0.f};

#pragma unroll
    for (int kk = 0; kk < 2; kk++) {
        bf16x8 af[4], bfr[4];
#pragma unroll
        for (int m = 0; m < 4; m++) {
            const float* p = Axd + (size_t)(m0 + wr + m * 16 + lr) * XCOLS + kk * 32 + kq;
            af[m] = cvt8(*(const float4*)p, *(const float4*)(p + 4));
        }
#pragma unroll
        for (int n = 0; n < 4; n++)
            bfr[n] = *(const bf16x8*)(Bw + (size_t)(n0 + wc + n * 16 + lr) * DTRANK + kk * 32 + kq);
#pragma unroll
        for (int m = 0; m < 4; m++)
#pragma unroll
            for (int n = 0; n < 4; n++)
                acc[m][n] = __builtin_amdgcn_mfma_f32_16x16x32_bf16(af[m], bfr[n], acc[m][n], 0, 0, 0);
    }

    const int er = (lane >> 4) * 4;
    const int ec = lane & 15;
#pragma unroll
    for (int m = 0; m < 4; m++)
#pragma unroll
        for (int n = 0; n < 4; n++) {
            const int gcol = n0 + wc + n * 16 + ec;
            const float bv = bias[gcol];
#pragma unroll
            for (int r = 0; r < 4; r++) {
                float c = acc[m][n][r] + bv;
                c = (c > 20.f) ? c : log1pf(__expf(c));
                dtm[(size_t)(m0 + wr + m * 16 + er + r) * DINNER + gcol] = c;
            }
        }
}

// ---------------------------------------------------------------------------
// Depthwise causal conv (width 4) + bias + SiLU. Writes fp32 xc + bf16 xcb.
// ---------------------------------------------------------------------------
__global__ __launch_bounds__(256)
void conv_silu_kernel(const float* __restrict__ xz,
                      const float* __restrict__ conv_w,
                      const float* __restrict__ conv_b,
                      float* __restrict__ xc,
                      ushort_t* __restrict__ xcb)
{
    int idx = blockIdx.x * 256 + threadIdx.x;
    if (idx >= LSEQ * DINNER) return;
    int t = idx / DINNER;
    int d = idx - t * DINNER;
    float acc = conv_b[d];
#pragma unroll
    for (int j = 0; j < 4; j++) {
        int tt = t - 3 + j;
        if (tt >= 0) acc = fmaf(conv_w[d*4 + j], xz[(size_t)tt * (2*DINNER) + d], acc);
    }
    float v = siluf(acc);
    xc[idx] = v;
    xcb[idx] = f2bf(v);
}

// ---------------------------------------------------------------------------
// Chunked parallel selective scan, lane-owns-channel layout.
// ---------------------------------------------------------------------------
__global__ __launch_bounds__(256)
void scan_phase1(const float* __restrict__ dtm,
                 const float* __restrict__ xdbl,
                 const float* __restrict__ xc,
                 const float* __restrict__ A_log,
                 float* __restrict__ Aprod, float* __restrict__ hend)
{
    __shared__ float Bs[CL][16];
    const int tid = threadIdx.x;
    const int d = blockIdx.x * 256 + tid;
    const int c = blockIdx.y;
    const int t0 = c * CL;

    {
        int t = tid >> 3, n = (tid * 2) & 15;
        float2 v = *(const float2*)&xdbl[(size_t)(t0 + t) * XCOLS + DTRANK + n];
        Bs[t][n] = v.x; Bs[t][n + 1] = v.y;
    }

    float a[16];
#pragma unroll
    for (int q = 0; q < 4; q++) {
        f32x4 v = *(const f32x4*)&A_log[(size_t)d * DSTATE + q * 4];
#pragma unroll
        for (int j = 0; j < 4; j++) a[q * 4 + j] = -__expf(v[j]);
    }
    float h[16];
#pragma unroll
    for (int n = 0; n < 16; n++) h[n] = 0.f;
    float sdt = 0.f;

    __syncthreads();

    float dtv = dtm[(size_t)t0 * DINNER + d];
    float xv  = xc[(size_t)t0 * DINNER + d];
    for (int tt = 0; tt < CL; tt++) {
        int tn_ = t0 + ((tt + 1 < CL) ? tt + 1 : tt);
        float dtv_n = dtm[(size_t)tn_ * DINNER + d];
        float xv_n  = xc[(size_t)tn_ * DINNER + d];

        f32x4 Bq[4];
#pragma unroll
        for (int q = 0; q < 4; q++) Bq[q] = *(const f32x4*)&Bs[tt][q * 4];
        float dtx = dtv * xv;
        sdt += dtv;
#pragma unroll
        for (int n = 0; n < 16; n++) {
            float e = __expf(dtv * a[n]);
            h[n] = fmaf(e, h[n], dtx * Bq[n >> 2][n & 3]);
        }
        dtv = dtv_n; xv = xv_n;
    }

#pragma unroll
    for (int n = 0; n < 16; n++) {
        const size_t k = (size_t)c * SSTATE + (size_t)n * DINNER + d;
        hend[k]  = h[n];
        Aprod[k] = __expf(a[n] * sdt);
    }
}

__global__ __launch_bounds__(256)
void scan_phase2(const float* __restrict__ Aprod, float* __restrict__ hend)
{
    const int idx = blockIdx.x * 256 + threadIdx.x;
    float carry = 0.f;
#pragma unroll
    for (int c = 0; c < NC; c++) {
        const size_t k = (size_t)c * SSTATE + idx;
        float oh = hend[k];
        float oA = Aprod[k];
        hend[k] = carry;
        carry = fmaf(oA, carry, oh);
    }
}

__global__ __launch_bounds__(256)
void scan_phase3(const float* __restrict__ dtm,
                 const float* __restrict__ xdbl,
                 const float* __restrict__ xc,
                 const float* __restrict__ A_log,
                 const float* __restrict__ Dp,
                 const float* __restrict__ xz,
                 const float* __restrict__ hinit,
                 ushort_t* __restrict__ yb)
{
    __shared__ float Bs[CL][16];
    __shared__ float Cs[CL][16];
    const int tid = threadIdx.x;
    const int d = blockIdx.x * 256 + tid;
    const int c = blockIdx.y;
    const int t0 = c * CL;

    {
        int r = tid & 127;
        int t = r >> 2, n = (r * 4) & 15;
        const float* src = &xdbl[(size_t)(t0 + t) * XCOLS + DTRANK + ((tid < 128) ? 0 : DSTATE) + n];
        float4 v = *(const float4*)src;
        float* dst = (tid < 128) ? &Bs[t][n] : &Cs[t][n];
        dst[0] = v.x; dst[1] = v.y; dst[2] = v.z; dst[3] = v.w;
    }

    float a[16];
#pragma unroll
    for (int q = 0; q < 4; q++) {
        f32x4 v = *(const f32x4*)&A_log[(size_t)d * DSTATE + q * 4];
#pragma unroll
        for (int j = 0; j < 4; j++) a[q * 4 + j] = -__expf(v[j]);
    }
    const float Dv = Dp[d];
    float h[16];
#pragma unroll
    for (int n = 0; n < 16; n++)
        h[n] = hinit[(size_t)c * SSTATE + (size_t)n * DINNER + d];

    __syncthreads();

    float dtv = dtm[(size_t)t0 * DINNER + d];
    float xv  = xc[(size_t)t0 * DINNER + d];
    for (int tt = 0; tt < CL; tt++) {
        const int t = t0 + tt;
        int tn_ = t0 + ((tt + 1 < CL) ? tt + 1 : tt);
        float dtv_n = dtm[(size_t)tn_ * DINNER + d];
        float xv_n  = xc[(size_t)tn_ * DINNER + d];
        float zv    = xz[(size_t)t * (2 * DINNER) + DINNER + d];

        f32x4 Bq[4], Cq[4];
#pragma unroll
        for (int q = 0; q < 4; q++) {
            Bq[q] = *(const f32x4*)&Bs[tt][q * 4];
            Cq[q] = *(const f32x4*)&Cs[tt][q * 4];
        }
        float dtx = dtv * xv;
        float y = 0.f;
#pragma unroll
        for (int n = 0; n < 16; n++) {
            float e = __expf(dtv * a[n]);
            h[n] = fmaf(e, h[n], dtx * Bq[n >> 2][n & 3]);
            y = fmaf(h[n], Cq[n >> 2][n & 3], y);
        }
        yb[(size_t)t * DINNER + d] = f2bf((y + Dv * xv) * siluf(zv));
        dtv = dtv_n; xv = xv_n;
    }
}

// ---------------------------------------------------------------------------
extern "C" void kernel_launch(void* const* d_in, const int* in_sizes, int n_in,
                              void* d_out, int out_size, void* d_ws, size_t ws_size,
                              hipStream_t stream)
{
    const float* x      = (const float*)d_in[0];
    const float* W_in   = (const float*)d_in[1];
    const float* conv_w = (const float*)d_in[2];
    const float* conv_b = (const float*)d_in[3];
    const float* W_x    = (const float*)d_in[4];
    const float* W_dt   = (const float*)d_in[5];
    const float* b_dt   = (const float*)d_in[6];
    const float* A_log  = (const float*)d_in[7];
    const float* D_par  = (const float*)d_in[8];
    const float* W_out  = (const float*)d_in[9];
    float* out = (float*)d_out;
    float* ws  = (float*)d_ws;

    float* xz    = ws;                                   // 8M f32
    float* xc    = xz   + (size_t)LSEQ * 2 * DINNER;     // 4M f32
    float* xdbl  = xc   + (size_t)LSEQ * DINNER;         // 196608 f32
    float* dtm   = xdbl + (size_t)LSEQ * XCOLS;          // 4M f32
    float* Aprod = dtm  + (size_t)LSEQ * DINNER;         // 2M f32 (xcb alias)
    float* hend  = Aprod + (size_t)NC * SSTATE;          // 2M f32
    ushort_t* xb   = (ushort_t*)(hend + (size_t)NC * SSTATE);  // 2M bf16
    ushort_t* Wib  = xb  + (size_t)LSEQ * DMODEL;              // 4M bf16
    ushort_t* Wob  = Wib + (size_t)(2*DINNER) * DMODEL;        // 2M bf16
    ushort_t* yb   = Wob + (size_t)DMODEL * DINNER;            // 4M bf16
    ushort_t* Wxb  = yb  + (size_t)LSEQ * DINNER;              // 196608 bf16
    ushort_t* Wdtb = Wxb + (size_t)XCOLS * DINNER;             // 131072 bf16
    ushort_t* xcb  = (ushort_t*)Aprod;   // alias: live steps 2-4, Aprod live step 5+

    // 0. fused casts to bf16 (x, W_in, W_out, W_x, W_dt)
    {
        int c0 = LSEQ * DMODEL, c1 = 2 * DINNER * DMODEL, c2 = DMODEL * DINNER;
        int c3 = XCOLS * DINNER, c4 = DINNER * DTRANK;
        int total = c0 + c1 + c2 + c3 + c4;
        hipLaunchKernelGGL(cast5_kernel, dim3((total / 8 + 255) / 256), dim3(256), 0, stream,
                           x, xb, c0, W_in, Wib, c1, W_out, Wob, c2,
                           W_x, Wxb, c3, W_dt, Wdtb, c4);
    }

    // 1. in_proj: xz = x @ W_in^T  (2048 x 4096), bf16 MFMA (r5 structure)
    hipLaunchKernelGGL(gemm_bf16, dim3(LSEQ/128, (2*DINNER)/128), dim3(256), 0, stream,
                       xb, Wib, xz, LSEQ, 2*DINNER, DMODEL);

    // 2. depthwise conv + SiLU -> xc (fp32) + xcb (bf16)
    hipLaunchKernelGGL(conv_silu_kernel, dim3((LSEQ*DINNER)/256), dim3(256), 0, stream,
                       xz, conv_w, conv_b, xc, xcb);

    // 3. x_dbl = xc @ W_x^T  (2048 x 96), direct-fragment MFMA, split-K=16
    hipMemsetAsync(xdbl, 0, (size_t)LSEQ * XCOLS * sizeof(float), stream);
    hipLaunchKernelGGL(gemm_xdbl, dim3(LSEQ/128, 1, 16), dim3(256), 0, stream,
                       xcb, Wxb, xdbl);

    // 4. dt = softplus(x_dbl[:, :64] @ W_dt^T + b_dt), direct-fragment MFMA
    hipLaunchKernelGGL(gemm_dt, dim3(LSEQ/128, DINNER/128), dim3(256), 0, stream,
                       xdbl, Wdtb, b_dt, dtm);

    // 5. chunked parallel scan (lane-owns-channel); phase 3 writes bf16 y
    hipLaunchKernelGGL(scan_phase1, dim3(DINNER/256, NC), dim3(256), 0, stream,
                       dtm, xdbl, xc, A_log, Aprod, hend);
    hipLaunchKernelGGL(scan_phase2, dim3(SSTATE/256), dim3(256), 0, stream,
                       Aprod, hend);
    hipLaunchKernelGGL(scan_phase3, dim3(DINNER/256, NC), dim3(256), 0, stream,
                       dtm, xdbl, xc, A_log, D_par, xz, hend, yb);

    // 6. out = y @ W_out^T  (2048 x 1024), bf16 MFMA (r5 structure)
    hipLaunchKernelGGL(gemm_bf16, dim3(LSEQ/128, DMODEL/128), dim3(256), 0, stream,
                       yb, Wob, out, LSEQ, DMODEL, DINNER);
}

// Round 10
// 219.652 us; speedup vs baseline: 1.3455x; 1.0101x over previous
//
#include <hip/hip_runtime.h>
#include <math.h>

#define LSEQ   2048
#define DMODEL 1024
#define DINNER 2048
#define DSTATE 16
#define DTRANK 64
#define XCOLS  96   // dt_rank + 2*d_state
#define CL     32   // scan chunk length
#define NC     (LSEQ/CL)          // 64 chunks
#define SSTATE (DINNER*DSTATE)    // 32768 scalar recurrences

typedef __attribute__((ext_vector_type(8))) short bf16x8;
typedef __attribute__((ext_vector_type(4))) float f32x4;
typedef unsigned short ushort_t;
typedef unsigned int uint_t;

__device__ __forceinline__ float siluf(float v) { return v / (1.f + __expf(-v)); }

// RNE float -> bf16 bits (finite inputs)
__device__ __forceinline__ ushort_t f2bf(float f) {
    uint_t u = __float_as_uint(f);
    u += 0x7FFFu + ((u >> 16) & 1u);
    return (ushort_t)(u >> 16);
}

__device__ __forceinline__ bf16x8 cvt8(float4 lo, float4 hi) {
    bf16x8 r;
    r[0] = (short)f2bf(lo.x); r[1] = (short)f2bf(lo.y);
    r[2] = (short)f2bf(lo.z); r[3] = (short)f2bf(lo.w);
    r[4] = (short)f2bf(hi.x); r[5] = (short)f2bf(hi.y);
    r[6] = (short)f2bf(hi.z); r[7] = (short)f2bf(hi.w);
    return r;
}

// ---------------------------------------------------------------------------
// fused f32 -> bf16 cast for 5 tensors, 8 elements/thread. sizes % 8 == 0.
// ---------------------------------------------------------------------------
__global__ __launch_bounds__(256)
void cast5_kernel(const float* __restrict__ s0, ushort_t* __restrict__ d0, int c0,
                  const float* __restrict__ s1, ushort_t* __restrict__ d1, int c1,
                  const float* __restrict__ s2, ushort_t* __restrict__ d2, int c2,
                  const float* __restrict__ s3, ushort_t* __restrict__ d3, int c3,
                  const float* __restrict__ s4, ushort_t* __restrict__ d4, int c4)
{
    int i = (blockIdx.x * 256 + threadIdx.x) * 8;
    const float* s; ushort_t* d;
    if (i < c0)                { s = s0 + i;                  d = d0 + i; }
    else if (i < c0+c1)        { s = s1 + (i-c0);             d = d1 + (i-c0); }
    else if (i < c0+c1+c2)     { s = s2 + (i-c0-c1);          d = d2 + (i-c0-c1); }
    else if (i < c0+c1+c2+c3)  { s = s3 + (i-c0-c1-c2);       d = d3 + (i-c0-c1-c2); }
    else if (i < c0+c1+c2+c3+c4) { s = s4 + (i-c0-c1-c2-c3);  d = d4 + (i-c0-c1-c2-c3); }
    else return;
    *(bf16x8*)d = cvt8(*(const float4*)s, *(const float4*)(s + 4));
}

// ---------------------------------------------------------------------------
// bf16 MFMA GEMM, 2-phase dbuf, BK=32, counted vmcnt(4).
// Split-K WITHOUT atomics: partial p stored at C + p*M*N (plain fp32 store).
// 128x128 tile, 4 waves (2x2) of 64x64. LDS 32 KB -> 5 blocks/CU possible;
// split-K grows the grid to reach 4 blocks/CU (staging rate ~3.6 B/cy/CU per
// co-resident block — r9 cross-round measurement).
// LDS per buf: [4 kb][128 row][8 elem] -> SQ_LDS_BANK_CONFLICT == 0.
// ---------------------------------------------------------------------------
__device__ __forceinline__ void stage_tile(const ushort_t* __restrict__ A,
                                           const ushort_t* __restrict__ B,
                                           ushort_t* As, ushort_t* Bs,
                                           int m0, int n0, int K, int k0, int tid)
{
#pragma unroll
    for (int j = 0; j < 2; j++) {
        const int c   = j * 256 + tid;   // 16B chunk index 0..511
        const int row = c & 127;
        const int kbi = c >> 7;          // 0..3
        __builtin_amdgcn_global_load_lds(
            (const __attribute__((address_space(1))) uint_t*)(A + (size_t)(m0 + row) * K + k0 + kbi * 8),
            (__attribute__((address_space(3))) uint_t*)((char*)As + c * 16), 16, 0, 0);
        __builtin_amdgcn_global_load_lds(
            (const __attribute__((address_space(1))) uint_t*)(B + (size_t)(n0 + row) * K + k0 + kbi * 8),
            (__attribute__((address_space(3))) uint_t*)((char*)Bs + c * 16), 16, 0, 0);
    }
}

template<int SPLITK>
__global__ __launch_bounds__(256)
void gemm_bf16(const ushort_t* __restrict__ A,
               const ushort_t* __restrict__ B,
               float* __restrict__ C, int M, int N, int K)
{
    __shared__ ushort_t As[2][4096];
    __shared__ ushort_t Bs[2][4096];

    const int tid  = threadIdx.x;
    const int wid  = tid >> 6;
    const int lane = tid & 63;
    const int m0 = blockIdx.x * 128;
    const int n0 = blockIdx.y * 128;
    const int kcnt  = K / SPLITK;
    const int kbase = (SPLITK > 1) ? blockIdx.z * kcnt : 0;
    const int NT = kcnt / 32;
    float* Cp = C + (size_t)blockIdx.z * M * N;   // disjoint partial buffer
    const int wr = (wid >> 1) * 64;
    const int wc = (wid & 1) * 64;
    const int lr = lane & 15;
    const int kbq = lane >> 4;

    f32x4 acc[4][4];
#pragma unroll
    for (int m = 0; m < 4; m++)
#pragma unroll
        for (int n = 0; n < 4; n++)
            acc[m][n] = (f32x4){0.f, 0.f, 0.f, 0.f};

    stage_tile(A, B, As[0], Bs[0], m0, n0, K, kbase, tid);

    for (int t = 0; t < NT; t++) {
        const int cur = t & 1;
        if (t + 1 < NT) {
            stage_tile(A, B, As[cur ^ 1], Bs[cur ^ 1], m0, n0, K, kbase + (t + 1) * 32, tid);
            asm volatile("s_waitcnt vmcnt(4)" ::: "memory");
        } else {
            asm volatile("s_waitcnt vmcnt(0)" ::: "memory");
        }
        __builtin_amdgcn_s_barrier();
        __builtin_amdgcn_sched_barrier(0);

        bf16x8 af[4], bfr[4];
#pragma unroll
        for (int m = 0; m < 4; m++)
            af[m] = *(const bf16x8*)&As[cur][(kbq * 128 + wr + m * 16 + lr) * 8];
#pragma unroll
        for (int n = 0; n < 4; n++)
            bfr[n] = *(const bf16x8*)&Bs[cur][(kbq * 128 + wc + n * 16 + lr) * 8];
#pragma unroll
        for (int m = 0; m < 4; m++)
#pragma unroll
            for (int n = 0; n < 4; n++)
                acc[m][n] = __builtin_amdgcn_mfma_f32_16x16x32_bf16(af[m], bfr[n], acc[m][n], 0, 0, 0);

        __builtin_amdgcn_sched_barrier(0);
        __builtin_amdgcn_s_barrier();
    }

    const int er = (lane >> 4) * 4;
    const int ec = lane & 15;
#pragma unroll
    for (int m = 0; m < 4; m++) {
        const int grow = m0 + wr + m * 16 + er;
#pragma unroll
        for (int n = 0; n < 4; n++) {
            const int gcol = n0 + wc + n * 16 + ec;
#pragma unroll
            for (int r = 0; r < 4; r++)
                Cp[(size_t)(grow + r) * N + gcol] = acc[m][n][r];
        }
    }
}

// ---------------------------------------------------------------------------
// Sum 8 fp32 partials (each n elems) into out. float4 per thread.
// ---------------------------------------------------------------------------
__global__ __launch_bounds__(256)
void add8_kernel(const float* __restrict__ parts, float* __restrict__ out, int n)
{
    int i = (blockIdx.x * 256 + threadIdx.x) * 4;
    if (i >= n) return;
    float4 s = *(const float4*)(parts + i);
#pragma unroll
    for (int p = 1; p < 8; p++) {
        float4 v = *(const float4*)(parts + (size_t)p * n + i);
        s.x += v.x; s.y += v.y; s.z += v.z; s.w += v.w;
    }
    *(float4*)(out + i) = s;
}

// ---------------------------------------------------------------------------
// x_dbl GEMM: direct-fragment MFMA, split-K=16, fp32 atomics on 786 KB output.
// ---------------------------------------------------------------------------
__global__ __launch_bounds__(256)
void gemm_xdbl(const ushort_t* __restrict__ A,
               const ushort_t* __restrict__ B,
               float* __restrict__ Cout)
{
    const int tid = threadIdx.x, wid = tid >> 6, lane = tid & 63;
    const int m0 = blockIdx.x * 128;
    const int kbase = blockIdx.z * 128;
    const int wr = (wid >> 1) * 64;
    const int wc = (wid & 1) * 48;
    const int lr = lane & 15;
    const int kq = (lane >> 4) * 8;

    f32x4 acc[4][3];
#pragma unroll
    for (int m = 0; m < 4; m++)
#pragma unroll
        for (int n = 0; n < 3; n++)
            acc[m][n] = (f32x4){0.f, 0.f, 0.f, 0.f};

#pragma unroll
    for (int ks = 0; ks < 4; ks++) {
        const int k0 = kbase + ks * 32;
        bf16x8 af[4], bfr[3];
#pragma unroll
        for (int m = 0; m < 4; m++)
            af[m] = *(const bf16x8*)(A + (size_t)(m0 + wr + m * 16 + lr) * DINNER + k0 + kq);
#pragma unroll
        for (int n = 0; n < 3; n++)
            bfr[n] = *(const bf16x8*)(B + (size_t)(wc + n * 16 + lr) * DINNER + k0 + kq);
#pragma unroll
        for (int m = 0; m < 4; m++)
#pragma unroll
            for (int n = 0; n < 3; n++)
                acc[m][n] = __builtin_amdgcn_mfma_f32_16x16x32_bf16(af[m], bfr[n], acc[m][n], 0, 0, 0);
    }

    const int er = (lane >> 4) * 4;
    const int ec = lane & 15;
#pragma unroll
    for (int m = 0; m < 4; m++)
#pragma unroll
        for (int n = 0; n < 3; n++)
#pragma unroll
            for (int r = 0; r < 4; r++)
                atomicAdd(&Cout[(size_t)(m0 + wr + m * 16 + er + r) * XCOLS + wc + n * 16 + ec],
                          acc[m][n][r]);
}

// ---------------------------------------------------------------------------
// dt GEMM: dtm = softplus(xdbl[:, :64] @ Wdtb^T + b_dt), direct-fragment MFMA.
// ---------------------------------------------------------------------------
__global__ __launch_bounds__(256)
void gemm_dt(const float* __restrict__ Axd,
             const ushort_t* __restrict__ Bw,
             const float* __restrict__ bias,
             float* __restrict__ dtm)
{
    const int tid = threadIdx.x, wid = tid >> 6, lane = tid & 63;
    const int m0 = blockIdx.x * 128;
    const int n0 = blockIdx.y * 128;
    const int wr = (wid >> 1) * 64;
    const int wc = (wid & 1) * 64;
    const int lr = lane & 15;
    const int kq = (lane >> 4) * 8;

    f32x4 acc[4][4];
#pragma unroll
    for (int m = 0; m < 4; m++)
#pragma unroll
        for (int n = 0; n < 4; n++)
            acc[m][n] = (f32x4){0.f, 0.f, 0.f, 0.f};

#pragma unroll
    for (int kk = 0; kk < 2; kk++) {
        bf16x8 af[4], bfr[4];
#pragma unroll
        for (int m = 0; m < 4; m++) {
            const float* p = Axd + (size_t)(m0 + wr + m * 16 + lr) * XCOLS + kk * 32 + kq;
            af[m] = cvt8(*(const float4*)p, *(const float4*)(p + 4));
        }
#pragma unroll
        for (int n = 0; n < 4; n++)
            bfr[n] = *(const bf16x8*)(Bw + (size_t)(n0 + wc + n * 16 + lr) * DTRANK + kk * 32 + kq);
#pragma unroll
        for (int m = 0; m < 4; m++)
#pragma unroll
            for (int n = 0; n < 4; n++)
                acc[m][n] = __builtin_amdgcn_mfma_f32_16x16x32_bf16(af[m], bfr[n], acc[m][n], 0, 0, 0);
    }

    const int er = (lane >> 4) * 4;
    const int ec = lane & 15;
#pragma unroll
    for (int m = 0; m < 4; m++)
#pragma unroll
        for (int n = 0; n < 4; n++) {
            const int gcol = n0 + wc + n * 16 + ec;
            const float bv = bias[gcol];
#pragma unroll
            for (int r = 0; r < 4; r++) {
                float c = acc[m][n][r] + bv;
                c = (c > 20.f) ? c : log1pf(__expf(c));
                dtm[(size_t)(m0 + wr + m * 16 + er + r) * DINNER + gcol] = c;
            }
        }
}

// ---------------------------------------------------------------------------
// Depthwise causal conv + bias + SiLU, fused combine of xz split-K partials.
// Writes fp32 xc + bf16 xcb.
// ---------------------------------------------------------------------------
__global__ __launch_bounds__(256)
void conv_silu_kernel(const float* __restrict__ xz,
                      const float* __restrict__ xz1, int addz,
                      const float* __restrict__ conv_w,
                      const float* __restrict__ conv_b,
                      float* __restrict__ xc,
                      ushort_t* __restrict__ xcb)
{
    int idx = blockIdx.x * 256 + threadIdx.x;
    if (idx >= LSEQ * DINNER) return;
    int t = idx / DINNER;
    int d = idx - t * DINNER;
    float acc = conv_b[d];
#pragma unroll
    for (int j = 0; j < 4; j++) {
        int tt = t - 3 + j;
        if (tt >= 0) {
            float v = xz[(size_t)tt * (2*DINNER) + d];
            if (addz) v += xz1[(size_t)tt * (2*DINNER) + d];
            acc = fmaf(conv_w[d*4 + j], v, acc);
        }
    }
    float v = siluf(acc);
    xc[idx] = v;
    xcb[idx] = f2bf(v);
}

// ---------------------------------------------------------------------------
// Chunked parallel selective scan, lane-owns-channel layout.
// ---------------------------------------------------------------------------
__global__ __launch_bounds__(256)
void scan_phase1(const float* __restrict__ dtm,
                 const float* __restrict__ xdbl,
                 const float* __restrict__ xc,
                 const float* __restrict__ A_log,
                 float* __restrict__ Aprod, float* __restrict__ hend)
{
    __shared__ float Bs[CL][16];
    const int tid = threadIdx.x;
    const int d = blockIdx.x * 256 + tid;
    const int c = blockIdx.y;
    const int t0 = c * CL;

    {
        int t = tid >> 3, n = (tid * 2) & 15;
        float2 v = *(const float2*)&xdbl[(size_t)(t0 + t) * XCOLS + DTRANK + n];
        Bs[t][n] = v.x; Bs[t][n + 1] = v.y;
    }

    float a[16];
#pragma unroll
    for (int q = 0; q < 4; q++) {
        f32x4 v = *(const f32x4*)&A_log[(size_t)d * DSTATE + q * 4];
#pragma unroll
        for (int j = 0; j < 4; j++) a[q * 4 + j] = -__expf(v[j]);
    }
    float h[16];
#pragma unroll
    for (int n = 0; n < 16; n++) h[n] = 0.f;
    float sdt = 0.f;

    __syncthreads();

    float dtv = dtm[(size_t)t0 * DINNER + d];
    float xv  = xc[(size_t)t0 * DINNER + d];
    for (int tt = 0; tt < CL; tt++) {
        int tn_ = t0 + ((tt + 1 < CL) ? tt + 1 : tt);
        float dtv_n = dtm[(size_t)tn_ * DINNER + d];
        float xv_n  = xc[(size_t)tn_ * DINNER + d];

        f32x4 Bq[4];
#pragma unroll
        for (int q = 0; q < 4; q++) Bq[q] = *(const f32x4*)&Bs[tt][q * 4];
        float dtx = dtv * xv;
        sdt += dtv;
#pragma unroll
        for (int n = 0; n < 16; n++) {
            float e = __expf(dtv * a[n]);
            h[n] = fmaf(e, h[n], dtx * Bq[n >> 2][n & 3]);
        }
        dtv = dtv_n; xv = xv_n;
    }

#pragma unroll
    for (int n = 0; n < 16; n++) {
        const size_t k = (size_t)c * SSTATE + (size_t)n * DINNER + d;
        hend[k]  = h[n];
        Aprod[k] = __expf(a[n] * sdt);
    }
}

__global__ __launch_bounds__(256)
void scan_phase2(const float* __restrict__ Aprod, float* __restrict__ hend)
{
    const int idx = blockIdx.x * 256 + threadIdx.x;
    float carry = 0.f;
#pragma unroll
    for (int c = 0; c < NC; c++) {
        const size_t k = (size_t)c * SSTATE + idx;
        float oh = hend[k];
        float oA = Aprod[k];
        hend[k] = carry;
        carry = fmaf(oA, carry, oh);
    }
}

__global__ __launch_bounds__(256)
void scan_phase3(const float* __restrict__ dtm,
                 const float* __restrict__ xdbl,
                 const float* __restrict__ xc,
                 const float* __restrict__ A_log,
                 const float* __restrict__ Dp,
                 const float* __restrict__ xz,
                 const float* __restrict__ xz1, int addz,
                 const float* __restrict__ hinit,
                 ushort_t* __restrict__ yb)
{
    __shared__ float Bs[CL][16];
    __shared__ float Cs[CL][16];
    const int tid = threadIdx.x;
    const int d = blockIdx.x * 256 + tid;
    const int c = blockIdx.y;
    const int t0 = c * CL;

    {
        int r = tid & 127;
        int t = r >> 2, n = (r * 4) & 15;
        const float* src = &xdbl[(size_t)(t0 + t) * XCOLS + DTRANK + ((tid < 128) ? 0 : DSTATE) + n];
        float4 v = *(const float4*)src;
        float* dst = (tid < 128) ? &Bs[t][n] : &Cs[t][n];
        dst[0] = v.x; dst[1] = v.y; dst[2] = v.z; dst[3] = v.w;
    }

    float a[16];
#pragma unroll
    for (int q = 0; q < 4; q++) {
        f32x4 v = *(const f32x4*)&A_log[(size_t)d * DSTATE + q * 4];
#pragma unroll
        for (int j = 0; j < 4; j++) a[q * 4 + j] = -__expf(v[j]);
    }
    const float Dv = Dp[d];
    float h[16];
#pragma unroll
    for (int n = 0; n < 16; n++)
        h[n] = hinit[(size_t)c * SSTATE + (size_t)n * DINNER + d];

    __syncthreads();

    float dtv = dtm[(size_t)t0 * DINNER + d];
    float xv  = xc[(size_t)t0 * DINNER + d];
    for (int tt = 0; tt < CL; tt++) {
        const int t = t0 + tt;
        int tn_ = t0 + ((tt + 1 < CL) ? tt + 1 : tt);
        float dtv_n = dtm[(size_t)tn_ * DINNER + d];
        float xv_n  = xc[(size_t)tn_ * DINNER + d];
        float zv    = xz[(size_t)t * (2 * DINNER) + DINNER + d];
        if (addz) zv += xz1[(size_t)t * (2 * DINNER) + DINNER + d];

        f32x4 Bq[4], Cq[4];
#pragma unroll
        for (int q = 0; q < 4; q++) {
            Bq[q] = *(const f32x4*)&Bs[tt][q * 4];
            Cq[q] = *(const f32x4*)&Cs[tt][q * 4];
        }
        float dtx = dtv * xv;
        float y = 0.f;
#pragma unroll
        for (int n = 0; n < 16; n++) {
            float e = __expf(dtv * a[n]);
            h[n] = fmaf(e, h[n], dtx * Bq[n >> 2][n & 3]);
            y = fmaf(h[n], Cq[n >> 2][n & 3], y);
        }
        yb[(size_t)t * DINNER + d] = f2bf((y + Dv * xv) * siluf(zv));
        dtv = dtv_n; xv = xv_n;
    }
}

// ---------------------------------------------------------------------------
extern "C" void kernel_launch(void* const* d_in, const int* in_sizes, int n_in,
                              void* d_out, int out_size, void* d_ws, size_t ws_size,
                              hipStream_t stream)
{
    const float* x      = (const float*)d_in[0];
    const float* W_in   = (const float*)d_in[1];
    const float* conv_w = (const float*)d_in[2];
    const float* conv_b = (const float*)d_in[3];
    const float* W_x    = (const float*)d_in[4];
    const float* W_dt   = (const float*)d_in[5];
    const float* b_dt   = (const float*)d_in[6];
    const float* A_log  = (const float*)d_in[7];
    const float* D_par  = (const float*)d_in[8];
    const float* W_out  = (const float*)d_in[9];
    float* out = (float*)d_out;
    float* ws  = (float*)d_ws;

    float* xz    = ws;                                   // 8M f32
    float* xc    = xz   + (size_t)LSEQ * 2 * DINNER;     // 4M f32
    float* xdbl  = xc   + (size_t)LSEQ * DINNER;         // 196608 f32
    float* dtm   = xdbl + (size_t)LSEQ * XCOLS;          // 4M f32
    float* Aprod = dtm  + (size_t)LSEQ * DINNER;         // 2M f32 (xcb alias)
    float* hend  = Aprod + (size_t)NC * SSTATE;          // 2M f32
    ushort_t* xb   = (ushort_t*)(hend + (size_t)NC * SSTATE);  // 2M bf16
    ushort_t* Wib  = xb  + (size_t)LSEQ * DMODEL;              // 4M bf16
    ushort_t* Wob  = Wib + (size_t)(2*DINNER) * DMODEL;        // 2M bf16
    ushort_t* yb   = Wob + (size_t)DMODEL * DINNER;            // 4M bf16
    ushort_t* Wxb  = yb  + (size_t)LSEQ * DINNER;              // 196608 bf16
    ushort_t* Wdtb = Wxb + (size_t)XCOLS * DINNER;             // 131072 bf16
    ushort_t* xcb  = (ushort_t*)Aprod;   // alias: live steps 2-4; Aprod live 5+
    // in_proj SK2 second partial: appended at tail (+32 MB), guarded by ws_size
    float* xz1 = (float*)(Wdtb + (size_t)DINNER * DTRANK);
    const size_t need = (size_t)((char*)(xz1 + (size_t)LSEQ * 2 * DINNER) - (char*)ws);
    const int use_sk2 = (ws_size >= need) ? 1 : 0;
    // out_proj SK8 partials: reuse [xz .. dtm] (16.97M f32, all dead post-phase3)
    float* outp = ws;

    // 0. fused casts to bf16 (x, W_in, W_out, W_x, W_dt)
    {
        int c0 = LSEQ * DMODEL, c1 = 2 * DINNER * DMODEL, c2 = DMODEL * DINNER;
        int c3 = XCOLS * DINNER, c4 = DINNER * DTRANK;
        int total = c0 + c1 + c2 + c3 + c4;
        hipLaunchKernelGGL(cast5_kernel, dim3((total / 8 + 255) / 256), dim3(256), 0, stream,
                           x, xb, c0, W_in, Wib, c1, W_out, Wob, c2,
                           W_x, Wxb, c3, W_dt, Wdtb, c4);
    }

    // 1. in_proj: xz = x @ W_in^T  (2048 x 4096). SK2 partials (no atomics);
    //    combine fused into conv + phase3's z-gate.
    if (use_sk2) {
        // partial 0 -> xz, partial 1 -> xz1 (blockIdx.z * M*N offset from xz
        // would overlap xc; so launch the two halves as separate partial bases)
        hipLaunchKernelGGL((gemm_bf16<2>), dim3(LSEQ/128, (2*DINNER)/128, 1), dim3(256), 0, stream,
                           xb, Wib, xz, LSEQ, 2*DINNER, DMODEL);
        // second half: shift A,B by K/2 and write to xz1 via the same kernel
        hipLaunchKernelGGL((gemm_bf16<2>), dim3(LSEQ/128, (2*DINNER)/128, 1), dim3(256), 0, stream,
                           xb + DMODEL/2, Wib + DMODEL/2, xz1, LSEQ, 2*DINNER, DMODEL);
    } else {
        hipLaunchKernelGGL((gemm_bf16<1>), dim3(LSEQ/128, (2*DINNER)/128, 1), dim3(256), 0, stream,
                           xb, Wib, xz, LSEQ, 2*DINNER, DMODEL);
    }

    // 2. depthwise conv + SiLU (+ SK2 combine) -> xc (fp32) + xcb (bf16)
    hipLaunchKernelGGL(conv_silu_kernel, dim3((LSEQ*DINNER)/256), dim3(256), 0, stream,
                       xz, xz1, use_sk2, conv_w, conv_b, xc, xcb);

    // 3. x_dbl = xc @ W_x^T  (2048 x 96), direct-fragment MFMA, split-K=16
    hipMemsetAsync(xdbl, 0, (size_t)LSEQ * XCOLS * sizeof(float), stream);
    hipLaunchKernelGGL(gemm_xdbl, dim3(LSEQ/128, 1, 16), dim3(256), 0, stream,
                       xcb, Wxb, xdbl);

    // 4. dt = softplus(x_dbl[:, :64] @ W_dt^T + b_dt), direct-fragment MFMA
    hipLaunchKernelGGL(gemm_dt, dim3(LSEQ/128, DINNER/128), dim3(256), 0, stream,
                       xdbl, Wdtb, b_dt, dtm);

    // 5. chunked parallel scan; phase 3 combines z-gate partials, writes bf16 y
    hipLaunchKernelGGL(scan_phase1, dim3(DINNER/256, NC), dim3(256), 0, stream,
                       dtm, xdbl, xc, A_log, Aprod, hend);
    hipLaunchKernelGGL(scan_phase2, dim3(SSTATE/256), dim3(256), 0, stream,
                       Aprod, hend);
    hipLaunchKernelGGL(scan_phase3, dim3(DINNER/256, NC), dim3(256), 0, stream,
                       dtm, xdbl, xc, A_log, D_par, xz, xz1, use_sk2, hend, yb);

    // 6. out = y @ W_out^T  (2048 x 1024), SK8 partials over dead ws + combine
    hipLaunchKernelGGL((gemm_bf16<8>), dim3(LSEQ/128, DMODEL/128, 8), dim3(256), 0, stream,
                       yb, Wob, outp, LSEQ, DMODEL, DINNER);
    hipLaunchKernelGGL(add8_kernel, dim3((LSEQ*DMODEL/4)/256), dim3(256), 0, stream,
                       outp, out, LSEQ*DMODEL);
}

// Round 11
// 214.439 us; speedup vs baseline: 1.3782x; 1.0243x over previous
//
#include <hip/hip_runtime.h>
#include <math.h>

#define LSEQ   2048
#define DMODEL 1024
#define DINNER 2048
#define DSTATE 16
#define DTRANK 64
#define XCOLS  96   // dt_rank + 2*d_state
#define CL     32   // scan chunk length
#define NC     (LSEQ/CL)          // 64 chunks
#define SSTATE (DINNER*DSTATE)    // 32768 scalar recurrences

typedef __attribute__((ext_vector_type(8))) short bf16x8;
typedef __attribute__((ext_vector_type(4))) float f32x4;
typedef unsigned short ushort_t;
typedef unsigned int uint_t;

__device__ __forceinline__ float siluf(float v) { return v / (1.f + __expf(-v)); }

// RNE float -> bf16 bits (finite inputs)
__device__ __forceinline__ ushort_t f2bf(float f) {
    uint_t u = __float_as_uint(f);
    u += 0x7FFFu + ((u >> 16) & 1u);
    return (ushort_t)(u >> 16);
}

__device__ __forceinline__ bf16x8 cvt8(float4 lo, float4 hi) {
    bf16x8 r;
    r[0] = (short)f2bf(lo.x); r[1] = (short)f2bf(lo.y);
    r[2] = (short)f2bf(lo.z); r[3] = (short)f2bf(lo.w);
    r[4] = (short)f2bf(hi.x); r[5] = (short)f2bf(hi.y);
    r[6] = (short)f2bf(hi.z); r[7] = (short)f2bf(hi.w);
    return r;
}

// ---------------------------------------------------------------------------
// fused f32 -> bf16 cast for 5 tensors + zero-fill of a 6th region.
// 8 elements/thread. sizes % 8 == 0. Replaces the 40-us hipMemsetAsync (r10).
// ---------------------------------------------------------------------------
__global__ __launch_bounds__(256)
void cast6_kernel(const float* __restrict__ s0, ushort_t* __restrict__ d0, int c0,
                  const float* __restrict__ s1, ushort_t* __restrict__ d1, int c1,
                  const float* __restrict__ s2, ushort_t* __restrict__ d2, int c2,
                  const float* __restrict__ s3, ushort_t* __restrict__ d3, int c3,
                  const float* __restrict__ s4, ushort_t* __restrict__ d4, int c4,
                  float* __restrict__ z0, int cz)
{
    int i = (blockIdx.x * 256 + threadIdx.x) * 8;
    int tot = c0 + c1 + c2 + c3 + c4;
    if (i < tot) {
        const float* s; ushort_t* d;
        if (i < c0)                { s = s0 + i;                  d = d0 + i; }
        else if (i < c0+c1)        { s = s1 + (i-c0);             d = d1 + (i-c0); }
        else if (i < c0+c1+c2)     { s = s2 + (i-c0-c1);          d = d2 + (i-c0-c1); }
        else if (i < c0+c1+c2+c3)  { s = s3 + (i-c0-c1-c2);       d = d3 + (i-c0-c1-c2); }
        else                       { s = s4 + (i-c0-c1-c2-c3);    d = d4 + (i-c0-c1-c2-c3); }
        *(bf16x8*)d = cvt8(*(const float4*)s, *(const float4*)(s + 4));
    } else if (i < tot + cz) {
        float* z = z0 + (i - tot);
        *(float4*)z       = make_float4(0.f, 0.f, 0.f, 0.f);
        *(float4*)(z + 4) = make_float4(0.f, 0.f, 0.f, 0.f);
    }
}

// ---------------------------------------------------------------------------
// bf16 MFMA GEMM, 2-phase dbuf, BK=32, counted vmcnt(4).
// Split-K WITHOUT atomics: partial z stored at C + z*partStride (plain fp32
// store; partStride passed since partials may be non-contiguous).
// 128x128 tile, 4 waves (2x2) of 64x64. LDS 32 KB.
// Staging-rate model (r9/r10): ~3.6 B/cy/CU per co-resident block; split-K
// grows the grid in ONE launch so 4 blocks/CU are co-resident (r10's two
// serialized launches defeated this — fixed here).
// LDS per buf: [4 kb][128 row][8 elem] -> SQ_LDS_BANK_CONFLICT == 0.
// ---------------------------------------------------------------------------
__device__ __forceinline__ void stage_tile(const ushort_t* __restrict__ A,
                                           const ushort_t* __restrict__ B,
                                           ushort_t* As, ushort_t* Bs,
                                           int m0, int n0, int K, int k0, int tid)
{
#pragma unroll
    for (int j = 0; j < 2; j++) {
        const int c   = j * 256 + tid;   // 16B chunk index 0..511
        const int row = c & 127;
        const int kbi = c >> 7;          // 0..3
        __builtin_amdgcn_global_load_lds(
            (const __attribute__((address_space(1))) uint_t*)(A + (size_t)(m0 + row) * K + k0 + kbi * 8),
            (__attribute__((address_space(3))) uint_t*)((char*)As + c * 16), 16, 0, 0);
        __builtin_amdgcn_global_load_lds(
            (const __attribute__((address_space(1))) uint_t*)(B + (size_t)(n0 + row) * K + k0 + kbi * 8),
            (__attribute__((address_space(3))) uint_t*)((char*)Bs + c * 16), 16, 0, 0);
    }
}

template<int SPLITK>
__global__ __launch_bounds__(256)
void gemm_bf16(const ushort_t* __restrict__ A,
               const ushort_t* __restrict__ B,
               float* __restrict__ C, int M, int N, int K, size_t partStride)
{
    __shared__ ushort_t As[2][4096];
    __shared__ ushort_t Bs[2][4096];

    const int tid  = threadIdx.x;
    const int wid  = tid >> 6;
    const int lane = tid & 63;
    const int m0 = blockIdx.x * 128;
    const int n0 = blockIdx.y * 128;
    const int kcnt  = K / SPLITK;
    const int kbase = (SPLITK > 1) ? blockIdx.z * kcnt : 0;
    const int NT = kcnt / 32;
    float* Cp = C + (size_t)blockIdx.z * partStride;
    const int wr = (wid >> 1) * 64;
    const int wc = (wid & 1) * 64;
    const int lr = lane & 15;
    const int kbq = lane >> 4;

    f32x4 acc[4][4];
#pragma unroll
    for (int m = 0; m < 4; m++)
#pragma unroll
        for (int n = 0; n < 4; n++)
            acc[m][n] = (f32x4){0.f, 0.f, 0.f, 0.f};

    stage_tile(A, B, As[0], Bs[0], m0, n0, K, kbase, tid);

    for (int t = 0; t < NT; t++) {
        const int cur = t & 1;
        if (t + 1 < NT) {
            stage_tile(A, B, As[cur ^ 1], Bs[cur ^ 1], m0, n0, K, kbase + (t + 1) * 32, tid);
            asm volatile("s_waitcnt vmcnt(4)" ::: "memory");
        } else {
            asm volatile("s_waitcnt vmcnt(0)" ::: "memory");
        }
        __builtin_amdgcn_s_barrier();
        __builtin_amdgcn_sched_barrier(0);

        bf16x8 af[4], bfr[4];
#pragma unroll
        for (int m = 0; m < 4; m++)
            af[m] = *(const bf16x8*)&As[cur][(kbq * 128 + wr + m * 16 + lr) * 8];
#pragma unroll
        for (int n = 0; n < 4; n++)
            bfr[n] = *(const bf16x8*)&Bs[cur][(kbq * 128 + wc + n * 16 + lr) * 8];
#pragma unroll
        for (int m = 0; m < 4; m++)
#pragma unroll
            for (int n = 0; n < 4; n++)
                acc[m][n] = __builtin_amdgcn_mfma_f32_16x16x32_bf16(af[m], bfr[n], acc[m][n], 0, 0, 0);

        __builtin_amdgcn_sched_barrier(0);
        __builtin_amdgcn_s_barrier();
    }

    const int er = (lane >> 4) * 4;
    const int ec = lane & 15;
#pragma unroll
    for (int m = 0; m < 4; m++) {
        const int grow = m0 + wr + m * 16 + er;
#pragma unroll
        for (int n = 0; n < 4; n++) {
            const int gcol = n0 + wc + n * 16 + ec;
#pragma unroll
            for (int r = 0; r < 4; r++)
                Cp[(size_t)(grow + r) * N + gcol] = acc[m][n][r];
        }
    }
}

// ---------------------------------------------------------------------------
// Sum 8 fp32 partials (each n elems) into out. float4 per thread.
// ---------------------------------------------------------------------------
__global__ __launch_bounds__(256)
void add8_kernel(const float* __restrict__ parts, float* __restrict__ out, int n)
{
    int i = (blockIdx.x * 256 + threadIdx.x) * 4;
    if (i >= n) return;
    float4 s = *(const float4*)(parts + i);
#pragma unroll
    for (int p = 1; p < 8; p++) {
        float4 v = *(const float4*)(parts + (size_t)p * n + i);
        s.x += v.x; s.y += v.y; s.z += v.z; s.w += v.w;
    }
    *(float4*)(out + i) = s;
}

// ---------------------------------------------------------------------------
// x_dbl GEMM: direct-fragment MFMA, split-K=16, fp32 atomics on 786 KB output.
// ---------------------------------------------------------------------------
__global__ __launch_bounds__(256)
void gemm_xdbl(const ushort_t* __restrict__ A,
               const ushort_t* __restrict__ B,
               float* __restrict__ Cout)
{
    const int tid = threadIdx.x, wid = tid >> 6, lane = tid & 63;
    const int m0 = blockIdx.x * 128;
    const int kbase = blockIdx.z * 128;
    const int wr = (wid >> 1) * 64;
    const int wc = (wid & 1) * 48;
    const int lr = lane & 15;
    const int kq = (lane >> 4) * 8;

    f32x4 acc[4][3];
#pragma unroll
    for (int m = 0; m < 4; m++)
#pragma unroll
        for (int n = 0; n < 3; n++)
            acc[m][n] = (f32x4){0.f, 0.f, 0.f, 0.f};

#pragma unroll
    for (int ks = 0; ks < 4; ks++) {
        const int k0 = kbase + ks * 32;
        bf16x8 af[4], bfr[3];
#pragma unroll
        for (int m = 0; m < 4; m++)
            af[m] = *(const bf16x8*)(A + (size_t)(m0 + wr + m * 16 + lr) * DINNER + k0 + kq);
#pragma unroll
        for (int n = 0; n < 3; n++)
            bfr[n] = *(const bf16x8*)(B + (size_t)(wc + n * 16 + lr) * DINNER + k0 + kq);
#pragma unroll
        for (int m = 0; m < 4; m++)
#pragma unroll
            for (int n = 0; n < 3; n++)
                acc[m][n] = __builtin_amdgcn_mfma_f32_16x16x32_bf16(af[m], bfr[n], acc[m][n], 0, 0, 0);
    }

    const int er = (lane >> 4) * 4;
    const int ec = lane & 15;
#pragma unroll
    for (int m = 0; m < 4; m++)
#pragma unroll
        for (int n = 0; n < 3; n++)
#pragma unroll
            for (int r = 0; r < 4; r++)
                atomicAdd(&Cout[(size_t)(m0 + wr + m * 16 + er + r) * XCOLS + wc + n * 16 + ec],
                          acc[m][n][r]);
}

// ---------------------------------------------------------------------------
// dt GEMM: dtm = softplus(xdbl[:, :64] @ Wdtb^T + b_dt), direct-fragment MFMA.
// ---------------------------------------------------------------------------
__global__ __launch_bounds__(256)
void gemm_dt(const float* __restrict__ Axd,
             const ushort_t* __restrict__ Bw,
             const float* __restrict__ bias,
             float* __restrict__ dtm)
{
    const int tid = threadIdx.x, wid = tid >> 6, lane = tid & 63;
    const int m0 = blockIdx.x * 128;
    const int n0 = blockIdx.y * 128;
    const int wr = (wid >> 1) * 64;
    const int wc = (wid & 1) * 64;
    const int lr = lane & 15;
    const int kq = (lane >> 4) * 8;

    f32x4 acc[4][4];
#pragma unroll
    for (int m = 0; m < 4; m++)
#pragma unroll
        for (int n = 0; n < 4; n++)
            acc[m][n] = (f32x4){0.f, 0.f, 0.f, 0.f};

#pragma unroll
    for (int kk = 0; kk < 2; kk++) {
        bf16x8 af[4], bfr[4];
#pragma unroll
        for (int m = 0; m < 4; m++) {
            const float* p = Axd + (size_t)(m0 + wr + m * 16 + lr) * XCOLS + kk * 32 + kq;
            af[m] = cvt8(*(const float4*)p, *(const float4*)(p + 4));
        }
#pragma unroll
        for (int n = 0; n < 4; n++)
            bfr[n] = *(const bf16x8*)(Bw + (size_t)(n0 + wc + n * 16 + lr) * DTRANK + kk * 32 + kq);
#pragma unroll
        for (int m = 0; m < 4; m++)
#pragma unroll
            for (int n = 0; n < 4; n++)
                acc[m][n] = __builtin_amdgcn_mfma_f32_16x16x32_bf16(af[m], bfr[n], acc[m][n], 0, 0, 0);
    }

    const int er = (lane >> 4) * 4;
    const int ec = lane & 15;
#pragma unroll
    for (int m = 0; m < 4; m++)
#pragma unroll
        for (int n = 0; n < 4; n++) {
            const int gcol = n0 + wc + n * 16 + ec;
            const float bv = bias[gcol];
#pragma unroll
            for (int r = 0; r < 4; r++) {
                float c = acc[m][n][r] + bv;
                c = (c > 20.f) ? c : log1pf(__expf(c));
                dtm[(size_t)(m0 + wr + m * 16 + er + r) * DINNER + gcol] = c;
            }
        }
}

// ---------------------------------------------------------------------------
// Depthwise causal conv + bias + SiLU, fused combine of xz split-K partials.
// Writes fp32 xc + bf16 xcb.
// ---------------------------------------------------------------------------
__global__ __launch_bounds__(256)
void conv_silu_kernel(const float* __restrict__ xz,
                      const float* __restrict__ xz1, int addz,
                      const float* __restrict__ conv_w,
                      const float* __restrict__ conv_b,
                      float* __restrict__ xc,
                      ushort_t* __restrict__ xcb)
{
    int idx = blockIdx.x * 256 + threadIdx.x;
    if (idx >= LSEQ * DINNER) return;
    int t = idx / DINNER;
    int d = idx - t * DINNER;
    float acc = conv_b[d];
#pragma unroll
    for (int j = 0; j < 4; j++) {
        int tt = t - 3 + j;
        if (tt >= 0) {
            float v = xz[(size_t)tt * (2*DINNER) + d];
            if (addz) v += xz1[(size_t)tt * (2*DINNER) + d];
            acc = fmaf(conv_w[d*4 + j], v, acc);
        }
    }
    float v = siluf(acc);
    xc[idx] = v;
    xcb[idx] = f2bf(v);
}

// ---------------------------------------------------------------------------
// Chunked parallel selective scan, lane-owns-channel layout.
// ---------------------------------------------------------------------------
__global__ __launch_bounds__(256)
void scan_phase1(const float* __restrict__ dtm,
                 const float* __restrict__ xdbl,
                 const float* __restrict__ xc,
                 const float* __restrict__ A_log,
                 float* __restrict__ Aprod, float* __restrict__ hend)
{
    __shared__ float Bs[CL][16];
    const int tid = threadIdx.x;
    const int d = blockIdx.x * 256 + tid;
    const int c = blockIdx.y;
    const int t0 = c * CL;

    {
        int t = tid >> 3, n = (tid * 2) & 15;
        float2 v = *(const float2*)&xdbl[(size_t)(t0 + t) * XCOLS + DTRANK + n];
        Bs[t][n] = v.x; Bs[t][n + 1] = v.y;
    }

    float a[16];
#pragma unroll
    for (int q = 0; q < 4; q++) {
        f32x4 v = *(const f32x4*)&A_log[(size_t)d * DSTATE + q * 4];
#pragma unroll
        for (int j = 0; j < 4; j++) a[q * 4 + j] = -__expf(v[j]);
    }
    float h[16];
#pragma unroll
    for (int n = 0; n < 16; n++) h[n] = 0.f;
    float sdt = 0.f;

    __syncthreads();

    float dtv = dtm[(size_t)t0 * DINNER + d];
    float xv  = xc[(size_t)t0 * DINNER + d];
    for (int tt = 0; tt < CL; tt++) {
        int tn_ = t0 + ((tt + 1 < CL) ? tt + 1 : tt);
        float dtv_n = dtm[(size_t)tn_ * DINNER + d];
        float xv_n  = xc[(size_t)tn_ * DINNER + d];

        f32x4 Bq[4];
#pragma unroll
        for (int q = 0; q < 4; q++) Bq[q] = *(const f32x4*)&Bs[tt][q * 4];
        float dtx = dtv * xv;
        sdt += dtv;
#pragma unroll
        for (int n = 0; n < 16; n++) {
            float e = __expf(dtv * a[n]);
            h[n] = fmaf(e, h[n], dtx * Bq[n >> 2][n & 3]);
        }
        dtv = dtv_n; xv = xv_n;
    }

#pragma unroll
    for (int n = 0; n < 16; n++) {
        const size_t k = (size_t)c * SSTATE + (size_t)n * DINNER + d;
        hend[k]  = h[n];
        Aprod[k] = __expf(a[n] * sdt);
    }
}

__global__ __launch_bounds__(256)
void scan_phase2(const float* __restrict__ Aprod, float* __restrict__ hend)
{
    const int idx = blockIdx.x * 256 + threadIdx.x;
    float carry = 0.f;
#pragma unroll
    for (int c = 0; c < NC; c++) {
        const size_t k = (size_t)c * SSTATE + idx;
        float oh = hend[k];
        float oA = Aprod[k];
        hend[k] = carry;
        carry = fmaf(oA, carry, oh);
    }
}

__global__ __launch_bounds__(256)
void scan_phase3(const float* __restrict__ dtm,
                 const float* __restrict__ xdbl,
                 const float* __restrict__ xc,
                 const float* __restrict__ A_log,
                 const float* __restrict__ Dp,
                 const float* __restrict__ xz,
                 const float* __restrict__ xz1, int addz,
                 const float* __restrict__ hinit,
                 ushort_t* __restrict__ yb)
{
    __shared__ float Bs[CL][16];
    __shared__ float Cs[CL][16];
    const int tid = threadIdx.x;
    const int d = blockIdx.x * 256 + tid;
    const int c = blockIdx.y;
    const int t0 = c * CL;

    {
        int r = tid & 127;
        int t = r >> 2, n = (r * 4) & 15;
        const float* src = &xdbl[(size_t)(t0 + t) * XCOLS + DTRANK + ((tid < 128) ? 0 : DSTATE) + n];
        float4 v = *(const float4*)src;
        float* dst = (tid < 128) ? &Bs[t][n] : &Cs[t][n];
        dst[0] = v.x; dst[1] = v.y; dst[2] = v.z; dst[3] = v.w;
    }

    float a[16];
#pragma unroll
    for (int q = 0; q < 4; q++) {
        f32x4 v = *(const f32x4*)&A_log[(size_t)d * DSTATE + q * 4];
#pragma unroll
        for (int j = 0; j < 4; j++) a[q * 4 + j] = -__expf(v[j]);
    }
    const float Dv = Dp[d];
    float h[16];
#pragma unroll
    for (int n = 0; n < 16; n++)
        h[n] = hinit[(size_t)c * SSTATE + (size_t)n * DINNER + d];

    __syncthreads();

    float dtv = dtm[(size_t)t0 * DINNER + d];
    float xv  = xc[(size_t)t0 * DINNER + d];
    for (int tt = 0; tt < CL; tt++) {
        const int t = t0 + tt;
        int tn_ = t0 + ((tt + 1 < CL) ? tt + 1 : tt);
        float dtv_n = dtm[(size_t)tn_ * DINNER + d];
        float xv_n  = xc[(size_t)tn_ * DINNER + d];
        float zv    = xz[(size_t)t * (2 * DINNER) + DINNER + d];
        if (addz) zv += xz1[(size_t)t * (2 * DINNER) + DINNER + d];

        f32x4 Bq[4], Cq[4];
#pragma unroll
        for (int q = 0; q < 4; q++) {
            Bq[q] = *(const f32x4*)&Bs[tt][q * 4];
            Cq[q] = *(const f32x4*)&Cs[tt][q * 4];
        }
        float dtx = dtv * xv;
        float y = 0.f;
#pragma unroll
        for (int n = 0; n < 16; n++) {
            float e = __expf(dtv * a[n]);
            h[n] = fmaf(e, h[n], dtx * Bq[n >> 2][n & 3]);
            y = fmaf(h[n], Cq[n >> 2][n & 3], y);
        }
        yb[(size_t)t * DINNER + d] = f2bf((y + Dv * xv) * siluf(zv));
        dtv = dtv_n; xv = xv_n;
    }
}

// ---------------------------------------------------------------------------
extern "C" void kernel_launch(void* const* d_in, const int* in_sizes, int n_in,
                              void* d_out, int out_size, void* d_ws, size_t ws_size,
                              hipStream_t stream)
{
    const float* x      = (const float*)d_in[0];
    const float* W_in   = (const float*)d_in[1];
    const float* conv_w = (const float*)d_in[2];
    const float* conv_b = (const float*)d_in[3];
    const float* W_x    = (const float*)d_in[4];
    const float* W_dt   = (const float*)d_in[5];
    const float* b_dt   = (const float*)d_in[6];
    const float* A_log  = (const float*)d_in[7];
    const float* D_par  = (const float*)d_in[8];
    const float* W_out  = (const float*)d_in[9];
    float* out = (float*)d_out;
    float* ws  = (float*)d_ws;

    float* xz    = ws;                                   // 8M f32
    float* xc    = xz   + (size_t)LSEQ * 2 * DINNER;     // 4M f32
    float* xdbl  = xc   + (size_t)LSEQ * DINNER;         // 196608 f32
    float* dtm   = xdbl + (size_t)LSEQ * XCOLS;          // 4M f32
    float* Aprod = dtm  + (size_t)LSEQ * DINNER;         // 2M f32 (xcb alias)
    float* hend  = Aprod + (size_t)NC * SSTATE;          // 2M f32
    ushort_t* xb   = (ushort_t*)(hend + (size_t)NC * SSTATE);  // 2M bf16
    ushort_t* Wib  = xb  + (size_t)LSEQ * DMODEL;              // 4M bf16
    ushort_t* Wob  = Wib + (size_t)(2*DINNER) * DMODEL;        // 2M bf16
    ushort_t* yb   = Wob + (size_t)DMODEL * DINNER;            // 4M bf16
    ushort_t* Wxb  = yb  + (size_t)LSEQ * DINNER;              // 196608 bf16
    ushort_t* Wdtb = Wxb + (size_t)XCOLS * DINNER;             // 131072 bf16
    ushort_t* xcb  = (ushort_t*)Aprod;   // alias: live steps 2-4; Aprod live 5+
    // in_proj SK2 second partial: appended at tail (+32 MB), guarded by ws_size
    float* xz1 = (float*)(Wdtb + (size_t)DINNER * DTRANK);
    const size_t need = (size_t)((char*)(xz1 + (size_t)LSEQ * 2 * DINNER) - (char*)ws);
    const int use_sk2 = (ws_size >= need) ? 1 : 0;
    // out_proj SK8 partials: reuse [xz .. dtm] (16.97M f32, all dead post-phase3)
    float* outp = ws;

    // 0. fused casts to bf16 (x, W_in, W_out, W_x, W_dt) + zero xdbl
    {
        int c0 = LSEQ * DMODEL, c1 = 2 * DINNER * DMODEL, c2 = DMODEL * DINNER;
        int c3 = XCOLS * DINNER, c4 = DINNER * DTRANK;
        int cz = LSEQ * XCOLS;
        int total = c0 + c1 + c2 + c3 + c4 + cz;
        hipLaunchKernelGGL(cast6_kernel, dim3((total / 8 + 255) / 256), dim3(256), 0, stream,
                           x, xb, c0, W_in, Wib, c1, W_out, Wob, c2,
                           W_x, Wxb, c3, W_dt, Wdtb, c4, xdbl, cz);
    }

    // 1. in_proj: xz = x @ W_in^T  (2048 x 4096). SK2 in ONE launch
    //    (1024 blocks co-resident); partial 1 at xz1; combine fused downstream.
    if (use_sk2) {
        hipLaunchKernelGGL((gemm_bf16<2>), dim3(LSEQ/128, (2*DINNER)/128, 2), dim3(256), 0, stream,
                           xb, Wib, xz, LSEQ, 2*DINNER, DMODEL, (size_t)(xz1 - xz));
    } else {
        hipLaunchKernelGGL((gemm_bf16<1>), dim3(LSEQ/128, (2*DINNER)/128, 1), dim3(256), 0, stream,
                           xb, Wib, xz, LSEQ, 2*DINNER, DMODEL, (size_t)0);
    }

    // 2. depthwise conv + SiLU (+ SK2 combine) -> xc (fp32) + xcb (bf16)
    hipLaunchKernelGGL(conv_silu_kernel, dim3((LSEQ*DINNER)/256), dim3(256), 0, stream,
                       xz, xz1, use_sk2, conv_w, conv_b, xc, xcb);

    // 3. x_dbl = xc @ W_x^T  (2048 x 96), direct-fragment MFMA, split-K=16
    //    (xdbl zeroed by cast6 at step 0)
    hipLaunchKernelGGL(gemm_xdbl, dim3(LSEQ/128, 1, 16), dim3(256), 0, stream,
                       xcb, Wxb, xdbl);

    // 4. dt = softplus(x_dbl[:, :64] @ W_dt^T + b_dt), direct-fragment MFMA
    hipLaunchKernelGGL(gemm_dt, dim3(LSEQ/128, DINNER/128), dim3(256), 0, stream,
                       xdbl, Wdtb, b_dt, dtm);

    // 5. chunked parallel scan; phase 3 combines z-gate partials, writes bf16 y
    hipLaunchKernelGGL(scan_phase1, dim3(DINNER/256, NC), dim3(256), 0, stream,
                       dtm, xdbl, xc, A_log, Aprod, hend);
    hipLaunchKernelGGL(scan_phase2, dim3(SSTATE/256), dim3(256), 0, stream,
                       Aprod, hend);
    hipLaunchKernelGGL(scan_phase3, dim3(DINNER/256, NC), dim3(256), 0, stream,
                       dtm, xdbl, xc, A_log, D_par, xz, xz1, use_sk2, hend, yb);

    // 6. out = y @ W_out^T  (2048 x 1024), SK8 partials over dead ws + combine
    hipLaunchKernelGGL((gemm_bf16<8>), dim3(LSEQ/128, DMODEL/128, 8), dim3(256), 0, stream,
                       yb, Wob, outp, LSEQ, DMODEL, DINNER, (size_t)(LSEQ*DMODEL));
    hipLaunchKernelGGL(add8_kernel, dim3((LSEQ*DMODEL/4)/256), dim3(256), 0, stream,
                       outp, out, LSEQ*DMODEL);
}

// Round 12
// 202.858 us; speedup vs baseline: 1.4568x; 1.0571x over previous
//
#include <hip/hip_runtime.h>
#include <math.h>

#define LSEQ   2048
#define DMODEL 1024
#define DINNER 2048
#define DSTATE 16
#define DTRANK 64
#define XCOLS  96   // dt_rank + 2*d_state
#define CL     32   // scan chunk length
#define NC     (LSEQ/CL)          // 64 chunks
#define SSTATE (DINNER*DSTATE)    // 32768 scalar recurrences

typedef __attribute__((ext_vector_type(8))) short bf16x8;
typedef __attribute__((ext_vector_type(4))) float f32x4;
typedef unsigned short ushort_t;
typedef unsigned int uint_t;

__device__ __forceinline__ float siluf(float v) { return v / (1.f + __expf(-v)); }

// RNE float -> bf16 bits (finite inputs)
__device__ __forceinline__ ushort_t f2bf(float f) {
    uint_t u = __float_as_uint(f);
    u += 0x7FFFu + ((u >> 16) & 1u);
    return (ushort_t)(u >> 16);
}

__device__ __forceinline__ bf16x8 cvt8(float4 lo, float4 hi) {
    bf16x8 r;
    r[0] = (short)f2bf(lo.x); r[1] = (short)f2bf(lo.y);
    r[2] = (short)f2bf(lo.z); r[3] = (short)f2bf(lo.w);
    r[4] = (short)f2bf(hi.x); r[5] = (short)f2bf(hi.y);
    r[6] = (short)f2bf(hi.z); r[7] = (short)f2bf(hi.w);
    return r;
}

// T1 XCD-aware block swizzle: blocks with original linear id ≡ k (mod 8) stay
// on XCD k and get a CONTIGUOUS range of remapped ids (bx-fastest decompose)
// so each XCD's L2 sees a small (by,bz)-slab of panels (3 MB vs 12 MB thrash).
// Requires nwg % 8 == 0 (all our grids satisfy this).
__device__ __forceinline__ void xcd_remap(int& bx, int& by, int& bz)
{
    const int gx = gridDim.x, gy = gridDim.y;
    const int flat = blockIdx.x + gx * (blockIdx.y + gy * blockIdx.z);
    const int q = (gx * gy * gridDim.z) >> 3;
    const int swz = (flat & 7) * q + (flat >> 3);
    bx = swz % gx;
    const int t = swz / gx;
    by = t % gy;
    bz = t / gy;
}

// ---------------------------------------------------------------------------
// fused f32 -> bf16 cast for 5 tensors + zero-fill of a 6th region.
// ---------------------------------------------------------------------------
__global__ __launch_bounds__(256)
void cast6_kernel(const float* __restrict__ s0, ushort_t* __restrict__ d0, int c0,
                  const float* __restrict__ s1, ushort_t* __restrict__ d1, int c1,
                  const float* __restrict__ s2, ushort_t* __restrict__ d2, int c2,
                  const float* __restrict__ s3, ushort_t* __restrict__ d3, int c3,
                  const float* __restrict__ s4, ushort_t* __restrict__ d4, int c4,
                  float* __restrict__ z0, int cz)
{
    int i = (blockIdx.x * 256 + threadIdx.x) * 8;
    int tot = c0 + c1 + c2 + c3 + c4;
    if (i < tot) {
        const float* s; ushort_t* d;
        if (i < c0)                { s = s0 + i;                  d = d0 + i; }
        else if (i < c0+c1)        { s = s1 + (i-c0);             d = d1 + (i-c0); }
        else if (i < c0+c1+c2)     { s = s2 + (i-c0-c1);          d = d2 + (i-c0-c1); }
        else if (i < c0+c1+c2+c3)  { s = s3 + (i-c0-c1-c2);       d = d3 + (i-c0-c1-c2); }
        else                       { s = s4 + (i-c0-c1-c2-c3);    d = d4 + (i-c0-c1-c2-c3); }
        *(bf16x8*)d = cvt8(*(const float4*)s, *(const float4*)(s + 4));
    } else if (i < tot + cz) {
        float* z = z0 + (i - tot);
        *(float4*)z       = make_float4(0.f, 0.f, 0.f, 0.f);
        *(float4*)(z + 4) = make_float4(0.f, 0.f, 0.f, 0.f);
    }
}

// ---------------------------------------------------------------------------
// bf16 MFMA GEMM, 2-phase dbuf, BK=32, counted vmcnt(4), T1 XCD swizzle.
// Split-K WITHOUT atomics: partial z at C + z*partStride (plain fp32 store).
// 128x128 tile, 4 waves (2x2) of 64x64.
// LDS per buf: [4 kb][128 row][8 elem] -> SQ_LDS_BANK_CONFLICT == 0.
// ---------------------------------------------------------------------------
__device__ __forceinline__ void stage_tile(const ushort_t* __restrict__ A,
                                           const ushort_t* __restrict__ B,
                                           ushort_t* As, ushort_t* Bs,
                                           int m0, int n0, int K, int k0, int tid)
{
#pragma unroll
    for (int j = 0; j < 2; j++) {
        const int c   = j * 256 + tid;   // 16B chunk index 0..511
        const int row = c & 127;
        const int kbi = c >> 7;          // 0..3
        __builtin_amdgcn_global_load_lds(
            (const __attribute__((address_space(1))) uint_t*)(A + (size_t)(m0 + row) * K + k0 + kbi * 8),
            (__attribute__((address_space(3))) uint_t*)((char*)As + c * 16), 16, 0, 0);
        __builtin_amdgcn_global_load_lds(
            (const __attribute__((address_space(1))) uint_t*)(B + (size_t)(n0 + row) * K + k0 + kbi * 8),
            (__attribute__((address_space(3))) uint_t*)((char*)Bs + c * 16), 16, 0, 0);
    }
}

template<int SPLITK>
__global__ __launch_bounds__(256)
void gemm_bf16(const ushort_t* __restrict__ A,
               const ushort_t* __restrict__ B,
               float* __restrict__ C, int M, int N, int K, size_t partStride)
{
    __shared__ ushort_t As[2][4096];
    __shared__ ushort_t Bs[2][4096];

    int bx, by, bz;
    xcd_remap(bx, by, bz);

    const int tid  = threadIdx.x;
    const int wid  = tid >> 6;
    const int lane = tid & 63;
    const int m0 = bx * 128;
    const int n0 = by * 128;
    const int kcnt  = K / SPLITK;
    const int kbase = (SPLITK > 1) ? bz * kcnt : 0;
    const int NT = kcnt / 32;
    float* Cp = C + (size_t)bz * partStride;
    const int wr = (wid >> 1) * 64;
    const int wc = (wid & 1) * 64;
    const int lr = lane & 15;
    const int kbq = lane >> 4;

    f32x4 acc[4][4];
#pragma unroll
    for (int m = 0; m < 4; m++)
#pragma unroll
        for (int n = 0; n < 4; n++)
            acc[m][n] = (f32x4){0.f, 0.f, 0.f, 0.f};

    stage_tile(A, B, As[0], Bs[0], m0, n0, K, kbase, tid);

    for (int t = 0; t < NT; t++) {
        const int cur = t & 1;
        if (t + 1 < NT) {
            stage_tile(A, B, As[cur ^ 1], Bs[cur ^ 1], m0, n0, K, kbase + (t + 1) * 32, tid);
            asm volatile("s_waitcnt vmcnt(4)" ::: "memory");
        } else {
            asm volatile("s_waitcnt vmcnt(0)" ::: "memory");
        }
        __builtin_amdgcn_s_barrier();
        __builtin_amdgcn_sched_barrier(0);

        bf16x8 af[4], bfr[4];
#pragma unroll
        for (int m = 0; m < 4; m++)
            af[m] = *(const bf16x8*)&As[cur][(kbq * 128 + wr + m * 16 + lr) * 8];
#pragma unroll
        for (int n = 0; n < 4; n++)
            bfr[n] = *(const bf16x8*)&Bs[cur][(kbq * 128 + wc + n * 16 + lr) * 8];
#pragma unroll
        for (int m = 0; m < 4; m++)
#pragma unroll
            for (int n = 0; n < 4; n++)
                acc[m][n] = __builtin_amdgcn_mfma_f32_16x16x32_bf16(af[m], bfr[n], acc[m][n], 0, 0, 0);

        __builtin_amdgcn_sched_barrier(0);
        __builtin_amdgcn_s_barrier();
    }

    const int er = (lane >> 4) * 4;
    const int ec = lane & 15;
#pragma unroll
    for (int m = 0; m < 4; m++) {
        const int grow = m0 + wr + m * 16 + er;
#pragma unroll
        for (int n = 0; n < 4; n++) {
            const int gcol = n0 + wc + n * 16 + ec;
#pragma unroll
            for (int r = 0; r < 4; r++)
                Cp[(size_t)(grow + r) * N + gcol] = acc[m][n][r];
        }
    }
}

// ---------------------------------------------------------------------------
// Sum NP fp32 partials (each n elems) into out. float4 per thread.
// ---------------------------------------------------------------------------
template<int NP>
__global__ __launch_bounds__(256)
void addp_kernel(const float* __restrict__ parts, float* __restrict__ out, int n)
{
    int i = (blockIdx.x * 256 + threadIdx.x) * 4;
    if (i >= n) return;
    float4 s = *(const float4*)(parts + i);
#pragma unroll
    for (int p = 1; p < NP; p++) {
        float4 v = *(const float4*)(parts + (size_t)p * n + i);
        s.x += v.x; s.y += v.y; s.z += v.z; s.w += v.w;
    }
    *(float4*)(out + i) = s;
}

// ---------------------------------------------------------------------------
// x_dbl GEMM: direct-fragment MFMA, split-K=16, fp32 atomics on 786 KB output.
// ---------------------------------------------------------------------------
__global__ __launch_bounds__(256)
void gemm_xdbl(const ushort_t* __restrict__ A,
               const ushort_t* __restrict__ B,
               float* __restrict__ Cout)
{
    const int tid = threadIdx.x, wid = tid >> 6, lane = tid & 63;
    const int m0 = blockIdx.x * 128;
    const int kbase = blockIdx.z * 128;
    const int wr = (wid >> 1) * 64;
    const int wc = (wid & 1) * 48;
    const int lr = lane & 15;
    const int kq = (lane >> 4) * 8;

    f32x4 acc[4][3];
#pragma unroll
    for (int m = 0; m < 4; m++)
#pragma unroll
        for (int n = 0; n < 3; n++)
            acc[m][n] = (f32x4){0.f, 0.f, 0.f, 0.f};

#pragma unroll
    for (int ks = 0; ks < 4; ks++) {
        const int k0 = kbase + ks * 32;
        bf16x8 af[4], bfr[3];
#pragma unroll
        for (int m = 0; m < 4; m++)
            af[m] = *(const bf16x8*)(A + (size_t)(m0 + wr + m * 16 + lr) * DINNER + k0 + kq);
#pragma unroll
        for (int n = 0; n < 3; n++)
            bfr[n] = *(const bf16x8*)(B + (size_t)(wc + n * 16 + lr) * DINNER + k0 + kq);
#pragma unroll
        for (int m = 0; m < 4; m++)
#pragma unroll
            for (int n = 0; n < 3; n++)
                acc[m][n] = __builtin_amdgcn_mfma_f32_16x16x32_bf16(af[m], bfr[n], acc[m][n], 0, 0, 0);
    }

    const int er = (lane >> 4) * 4;
    const int ec = lane & 15;
#pragma unroll
    for (int m = 0; m < 4; m++)
#pragma unroll
        for (int n = 0; n < 3; n++)
#pragma unroll
            for (int r = 0; r < 4; r++)
                atomicAdd(&Cout[(size_t)(m0 + wr + m * 16 + er + r) * XCOLS + wc + n * 16 + ec],
                          acc[m][n][r]);
}

// ---------------------------------------------------------------------------
// dt GEMM: dtm = softplus(xdbl[:, :64] @ Wdtb^T + b_dt), direct-fragment MFMA.
// ---------------------------------------------------------------------------
__global__ __launch_bounds__(256)
void gemm_dt(const float* __restrict__ Axd,
             const ushort_t* __restrict__ Bw,
             const float* __restrict__ bias,
             float* __restrict__ dtm)
{
    const int tid = threadIdx.x, wid = tid >> 6, lane = tid & 63;
    const int m0 = blockIdx.x * 128;
    const int n0 = blockIdx.y * 128;
    const int wr = (wid >> 1) * 64;
    const int wc = (wid & 1) * 64;
    const int lr = lane & 15;
    const int kq = (lane >> 4) * 8;

    f32x4 acc[4][4];
#pragma unroll
    for (int m = 0; m < 4; m++)
#pragma unroll
        for (int n = 0; n < 4; n++)
            acc[m][n] = (f32x4){0.f, 0.f, 0.f, 0.f};

#pragma unroll
    for (int kk = 0; kk < 2; kk++) {
        bf16x8 af[4], bfr[4];
#pragma unroll
        for (int m = 0; m < 4; m++) {
            const float* p = Axd + (size_t)(m0 + wr + m * 16 + lr) * XCOLS + kk * 32 + kq;
            af[m] = cvt8(*(const float4*)p, *(const float4*)(p + 4));
        }
#pragma unroll
        for (int n = 0; n < 4; n++)
            bfr[n] = *(const bf16x8*)(Bw + (size_t)(n0 + wc + n * 16 + lr) * DTRANK + kk * 32 + kq);
#pragma unroll
        for (int m = 0; m < 4; m++)
#pragma unroll
            for (int n = 0; n < 4; n++)
                acc[m][n] = __builtin_amdgcn_mfma_f32_16x16x32_bf16(af[m], bfr[n], acc[m][n], 0, 0, 0);
    }

    const int er = (lane >> 4) * 4;
    const int ec = lane & 15;
#pragma unroll
    for (int m = 0; m < 4; m++)
#pragma unroll
        for (int n = 0; n < 4; n++) {
            const int gcol = n0 + wc + n * 16 + ec;
            const float bv = bias[gcol];
#pragma unroll
            for (int r = 0; r < 4; r++) {
                float c = acc[m][n][r] + bv;
                c = (c > 20.f) ? c : log1pf(__expf(c));
                dtm[(size_t)(m0 + wr + m * 16 + er + r) * DINNER + gcol] = c;
            }
        }
}

// ---------------------------------------------------------------------------
// Depthwise causal conv + bias + SiLU, fused combine of xz split-K partials.
// ---------------------------------------------------------------------------
__global__ __launch_bounds__(256)
void conv_silu_kernel(const float* __restrict__ xz,
                      const float* __restrict__ xz1, int addz,
                      const float* __restrict__ conv_w,
                      const float* __restrict__ conv_b,
                      float* __restrict__ xc,
                      ushort_t* __restrict__ xcb)
{
    int idx = blockIdx.x * 256 + threadIdx.x;
    if (idx >= LSEQ * DINNER) return;
    int t = idx / DINNER;
    int d = idx - t * DINNER;
    float acc = conv_b[d];
#pragma unroll
    for (int j = 0; j < 4; j++) {
        int tt = t - 3 + j;
        if (tt >= 0) {
            float v = xz[(size_t)tt * (2*DINNER) + d];
            if (addz) v += xz1[(size_t)tt * (2*DINNER) + d];
            acc = fmaf(conv_w[d*4 + j], v, acc);
        }
    }
    float v = siluf(acc);
    xc[idx] = v;
    xcb[idx] = f2bf(v);
}

// ---------------------------------------------------------------------------
// Chunked parallel selective scan, lane-owns-channel layout.
// ---------------------------------------------------------------------------
__global__ __launch_bounds__(256)
void scan_phase1(const float* __restrict__ dtm,
                 const float* __restrict__ xdbl,
                 const float* __restrict__ xc,
                 const float* __restrict__ A_log,
                 float* __restrict__ Aprod, float* __restrict__ hend)
{
    __shared__ float Bs[CL][16];
    const int tid = threadIdx.x;
    const int d = blockIdx.x * 256 + tid;
    const int c = blockIdx.y;
    const int t0 = c * CL;

    {
        int t = tid >> 3, n = (tid * 2) & 15;
        float2 v = *(const float2*)&xdbl[(size_t)(t0 + t) * XCOLS + DTRANK + n];
        Bs[t][n] = v.x; Bs[t][n + 1] = v.y;
    }

    float a[16];
#pragma unroll
    for (int q = 0; q < 4; q++) {
        f32x4 v = *(const f32x4*)&A_log[(size_t)d * DSTATE + q * 4];
#pragma unroll
        for (int j = 0; j < 4; j++) a[q * 4 + j] = -__expf(v[j]);
    }
    float h[16];
#pragma unroll
    for (int n = 0; n < 16; n++) h[n] = 0.f;
    float sdt = 0.f;

    __syncthreads();

    float dtv = dtm[(size_t)t0 * DINNER + d];
    float xv  = xc[(size_t)t0 * DINNER + d];
    for (int tt = 0; tt < CL; tt++) {
        int tn_ = t0 + ((tt + 1 < CL) ? tt + 1 : tt);
        float dtv_n = dtm[(size_t)tn_ * DINNER + d];
        float xv_n  = xc[(size_t)tn_ * DINNER + d];

        f32x4 Bq[4];
#pragma unroll
        for (int q = 0; q < 4; q++) Bq[q] = *(const f32x4*)&Bs[tt][q * 4];
        float dtx = dtv * xv;
        sdt += dtv;
#pragma unroll
        for (int n = 0; n < 16; n++) {
            float e = __expf(dtv * a[n]);
            h[n] = fmaf(e, h[n], dtx * Bq[n >> 2][n & 3]);
        }
        dtv = dtv_n; xv = xv_n;
    }

#pragma unroll
    for (int n = 0; n < 16; n++) {
        const size_t k = (size_t)c * SSTATE + (size_t)n * DINNER + d;
        hend[k]  = h[n];
        Aprod[k] = __expf(a[n] * sdt);
    }
}

__global__ __launch_bounds__(256)
void scan_phase2(const float* __restrict__ Aprod, float* __restrict__ hend)
{
    const int idx = blockIdx.x * 256 + threadIdx.x;
    float carry = 0.f;
#pragma unroll
    for (int c = 0; c < NC; c++) {
        const size_t k = (size_t)c * SSTATE + idx;
        float oh = hend[k];
        float oA = Aprod[k];
        hend[k] = carry;
        carry = fmaf(oA, carry, oh);
    }
}

__global__ __launch_bounds__(256)
void scan_phase3(const float* __restrict__ dtm,
                 const float* __restrict__ xdbl,
                 const float* __restrict__ xc,
                 const float* __restrict__ A_log,
                 const float* __restrict__ Dp,
                 const float* __restrict__ xz,
                 const float* __restrict__ xz1, int addz,
                 const float* __restrict__ hinit,
                 ushort_t* __restrict__ yb)
{
    __shared__ float Bs[CL][16];
    __shared__ float Cs[CL][16];
    const int tid = threadIdx.x;
    const int d = blockIdx.x * 256 + tid;
    const int c = blockIdx.y;
    const int t0 = c * CL;

    {
        int r = tid & 127;
        int t = r >> 2, n = (r * 4) & 15;
        const float* src = &xdbl[(size_t)(t0 + t) * XCOLS + DTRANK + ((tid < 128) ? 0 : DSTATE) + n];
        float4 v = *(const float4*)src;
        float* dst = (tid < 128) ? &Bs[t][n] : &Cs[t][n];
        dst[0] = v.x; dst[1] = v.y; dst[2] = v.z; dst[3] = v.w;
    }

    float a[16];
#pragma unroll
    for (int q = 0; q < 4; q++) {
        f32x4 v = *(const f32x4*)&A_log[(size_t)d * DSTATE + q * 4];
#pragma unroll
        for (int j = 0; j < 4; j++) a[q * 4 + j] = -__expf(v[j]);
    }
    const float Dv = Dp[d];
    float h[16];
#pragma unroll
    for (int n = 0; n < 16; n++)
        h[n] = hinit[(size_t)c * SSTATE + (size_t)n * DINNER + d];

    __syncthreads();

    float dtv = dtm[(size_t)t0 * DINNER + d];
    float xv  = xc[(size_t)t0 * DINNER + d];
    for (int tt = 0; tt < CL; tt++) {
        const int t = t0 + tt;
        int tn_ = t0 + ((tt + 1 < CL) ? tt + 1 : tt);
        float dtv_n = dtm[(size_t)tn_ * DINNER + d];
        float xv_n  = xc[(size_t)tn_ * DINNER + d];
        float zv    = xz[(size_t)t * (2 * DINNER) + DINNER + d];
        if (addz) zv += xz1[(size_t)t * (2 * DINNER) + DINNER + d];

        f32x4 Bq[4], Cq[4];
#pragma unroll
        for (int q = 0; q < 4; q++) {
            Bq[q] = *(const f32x4*)&Bs[tt][q * 4];
            Cq[q] = *(const f32x4*)&Cs[tt][q * 4];
        }
        float dtx = dtv * xv;
        float y = 0.f;
#pragma unroll
        for (int n = 0; n < 16; n++) {
            float e = __expf(dtv * a[n]);
            h[n] = fmaf(e, h[n], dtx * Bq[n >> 2][n & 3]);
            y = fmaf(h[n], Cq[n >> 2][n & 3], y);
        }
        yb[(size_t)t * DINNER + d] = f2bf((y + Dv * xv) * siluf(zv));
        dtv = dtv_n; xv = xv_n;
    }
}

// ---------------------------------------------------------------------------
extern "C" void kernel_launch(void* const* d_in, const int* in_sizes, int n_in,
                              void* d_out, int out_size, void* d_ws, size_t ws_size,
                              hipStream_t stream)
{
    const float* x      = (const float*)d_in[0];
    const float* W_in   = (const float*)d_in[1];
    const float* conv_w = (const float*)d_in[2];
    const float* conv_b = (const float*)d_in[3];
    const float* W_x    = (const float*)d_in[4];
    const float* W_dt   = (const float*)d_in[5];
    const float* b_dt   = (const float*)d_in[6];
    const float* A_log  = (const float*)d_in[7];
    const float* D_par  = (const float*)d_in[8];
    const float* W_out  = (const float*)d_in[9];
    float* out = (float*)d_out;
    float* ws  = (float*)d_ws;

    float* xz    = ws;                                   // 8M f32
    float* xc    = xz   + (size_t)LSEQ * 2 * DINNER;     // 4M f32
    float* xdbl  = xc   + (size_t)LSEQ * DINNER;         // 196608 f32
    float* dtm   = xdbl + (size_t)LSEQ * XCOLS;          // 4M f32
    float* Aprod = dtm  + (size_t)LSEQ * DINNER;         // 2M f32 (xcb alias)
    float* hend  = Aprod + (size_t)NC * SSTATE;          // 2M f32
    ushort_t* xb   = (ushort_t*)(hend + (size_t)NC * SSTATE);  // 2M bf16
    ushort_t* Wib  = xb  + (size_t)LSEQ * DMODEL;              // 4M bf16
    ushort_t* Wob  = Wib + (size_t)(2*DINNER) * DMODEL;        // 2M bf16
    ushort_t* yb   = Wob + (size_t)DMODEL * DINNER;            // 4M bf16
    ushort_t* Wxb  = yb  + (size_t)LSEQ * DINNER;              // 196608 bf16
    ushort_t* Wdtb = Wxb + (size_t)XCOLS * DINNER;             // 131072 bf16
    ushort_t* xcb  = (ushort_t*)Aprod;   // alias: live steps 2-4; Aprod live 5+
    // in_proj SK2 second partial: appended at tail (+32 MB), guarded by ws_size
    float* xz1 = (float*)(Wdtb + (size_t)DINNER * DTRANK);
    const size_t need = (size_t)((char*)(xz1 + (size_t)LSEQ * 2 * DINNER) - (char*)ws);
    const int use_sk2 = (ws_size >= need) ? 1 : 0;
    // out_proj SK4 partials: reuse [xz ..] (dead post-phase3; needs 8.4M f32)
    float* outp = ws;

    // 0. fused casts to bf16 (x, W_in, W_out, W_x, W_dt) + zero xdbl
    {
        int c0 = LSEQ * DMODEL, c1 = 2 * DINNER * DMODEL, c2 = DMODEL * DINNER;
        int c3 = XCOLS * DINNER, c4 = DINNER * DTRANK;
        int cz = LSEQ * XCOLS;
        int total = c0 + c1 + c2 + c3 + c4 + cz;
        hipLaunchKernelGGL(cast6_kernel, dim3((total / 8 + 255) / 256), dim3(256), 0, stream,
                           x, xb, c0, W_in, Wib, c1, W_out, Wob, c2,
                           W_x, Wxb, c3, W_dt, Wdtb, c4, xdbl, cz);
    }

    // 1. in_proj: xz = x @ W_in^T  (2048 x 4096). SK2, one launch, XCD-swizzled.
    if (use_sk2) {
        hipLaunchKernelGGL((gemm_bf16<2>), dim3(LSEQ/128, (2*DINNER)/128, 2), dim3(256), 0, stream,
                           xb, Wib, xz, LSEQ, 2*DINNER, DMODEL, (size_t)(xz1 - xz));
    } else {
        hipLaunchKernelGGL((gemm_bf16<1>), dim3(LSEQ/128, (2*DINNER)/128, 1), dim3(256), 0, stream,
                           xb, Wib, xz, LSEQ, 2*DINNER, DMODEL, (size_t)0);
    }

    // 2. depthwise conv + SiLU (+ SK2 combine) -> xc (fp32) + xcb (bf16)
    hipLaunchKernelGGL(conv_silu_kernel, dim3((LSEQ*DINNER)/256), dim3(256), 0, stream,
                       xz, xz1, use_sk2, conv_w, conv_b, xc, xcb);

    // 3. x_dbl = xc @ W_x^T  (2048 x 96), direct-fragment MFMA, split-K=16
    hipLaunchKernelGGL(gemm_xdbl, dim3(LSEQ/128, 1, 16), dim3(256), 0, stream,
                       xcb, Wxb, xdbl);

    // 4. dt = softplus(x_dbl[:, :64] @ W_dt^T + b_dt), direct-fragment MFMA
    hipLaunchKernelGGL(gemm_dt, dim3(LSEQ/128, DINNER/128), dim3(256), 0, stream,
                       xdbl, Wdtb, b_dt, dtm);

    // 5. chunked parallel scan; phase 3 combines z-gate partials, writes bf16 y
    hipLaunchKernelGGL(scan_phase1, dim3(DINNER/256, NC), dim3(256), 0, stream,
                       dtm, xdbl, xc, A_log, Aprod, hend);
    hipLaunchKernelGGL(scan_phase2, dim3(SSTATE/256), dim3(256), 0, stream,
                       Aprod, hend);
    hipLaunchKernelGGL(scan_phase3, dim3(DINNER/256, NC), dim3(256), 0, stream,
                       dtm, xdbl, xc, A_log, D_par, xz, xz1, use_sk2, hend, yb);

    // 6. out = y @ W_out^T  (2048 x 1024), SK4 XCD-swizzled partials + add4
    hipLaunchKernelGGL((gemm_bf16<4>), dim3(LSEQ/128, DMODEL/128, 4), dim3(256), 0, stream,
                       yb, Wob, outp, LSEQ, DMODEL, DINNER, (size_t)(LSEQ*DMODEL));
    hipLaunchKernelGGL((addp_kernel<4>), dim3((LSEQ*DMODEL/4)/256), dim3(256), 0, stream,
                       outp, out, LSEQ*DMODEL);
}